// Round 2
// baseline (1599.396 us; speedup 1.0000x reference)
//
#include <hip/hip_runtime.h>
#include <math.h>

// ---------------- constants ----------------
#define FDIM 128          // F_IN == HEADS*C_HID == 128
#define NEG_SLOPE 0.2f
#define LP_ALPHA 0.5f
#define NGRAPHS 32
#define POOLF 384         // 3*128
#define MLP_H 256
#define OUT_F 128

#define LRELU(z) ((z) > 0.0f ? (z) : NEG_SLOPE * (z))

// ---------------- CSR build ----------------
__global__ void count_deg_k(const int* __restrict__ dst, int* __restrict__ deg, int E) {
    int e = blockIdx.x * blockDim.x + threadIdx.x;
    if (e < E) atomicAdd(&deg[dst[e]], 1);
}

__global__ void scan_excl_k(const int* __restrict__ deg, int* __restrict__ row_ptr, int n) {
    __shared__ int part[1024];
    int tid = threadIdx.x;
    int chunk = (n + 1023) >> 10;
    int s0 = tid * chunk;
    int s1 = min(s0 + chunk, n);
    int sum = 0;
    for (int i = s0; i < s1; ++i) sum += deg[i];
    part[tid] = sum;
    __syncthreads();
    for (int off = 1; off < 1024; off <<= 1) {
        int v = (tid >= off) ? part[tid - off] : 0;
        __syncthreads();
        part[tid] += v;
        __syncthreads();
    }
    int run = (tid == 0) ? 0 : part[tid - 1];
    for (int i = s0; i < s1; ++i) { row_ptr[i] = run; run += deg[i]; }
    if (tid == 1023) row_ptr[n] = part[1023];
}

// derive self-loop CSR offsets (each node contributes exactly 1 self-loop),
// seed the self-loop entry first, init fill counters and dinv.
__global__ void node_init_k(const int* __restrict__ deg, const int* __restrict__ row_lp,
                            int* __restrict__ row_sl, int* __restrict__ list_sl,
                            int* __restrict__ fill_sl, float* __restrict__ dinv, int N) {
    int i = blockIdx.x * blockDim.x + threadIdx.x;
    if (i > N) return;
    if (i == N) { row_sl[N] = row_lp[N] + N; return; }
    int rs = row_lp[i] + i;
    row_sl[i] = rs;
    list_sl[rs] = i;          // self-loop first in each segment
    fill_sl[i] = 1;
    int d = deg[i];
    dinv[i] = (d > 0) ? (1.0f / sqrtf((float)d)) : 0.0f;
}

// one pass fills both adjacency lists (stores SOURCE node ids, grouped by dst)
__global__ void scatter_both_k(const int* __restrict__ src, const int* __restrict__ dst,
                               const int* __restrict__ row_lp, const int* __restrict__ row_sl,
                               int* __restrict__ fill_lp, int* __restrict__ fill_sl,
                               int* __restrict__ list_lp, int* __restrict__ list_sl, int E) {
    int e = blockIdx.x * blockDim.x + threadIdx.x;
    if (e >= E) return;
    int d = dst[e], s = src[e];
    int p1 = atomicAdd(&fill_lp[d], 1);
    list_lp[row_lp[d] + p1] = s;
    int p2 = atomicAdd(&fill_sl[d], 1);
    list_sl[row_sl[d] + p2] = s;
}

// ---------------- node GEMM: Y[N,128] = X[N,128] @ W[128,128] ----------------
// 64 rows x 128 cols per block, 256 threads, 8x4 register tile per thread.
__global__ __launch_bounds__(256) void gemm128_k(const float* __restrict__ X,
                                                 const float* __restrict__ W,
                                                 float* __restrict__ Y, int N) {
    __shared__ float Ws[FDIM * FDIM];     // 64 KB, [k][col]
    __shared__ float Xs[FDIM][68];        // 34 KB, transposed [k][r], padded
    int t = threadIdx.x;
    const float4* W4 = (const float4*)W;
    float4* Ws4 = (float4*)Ws;
    for (int k = t; k < FDIM * FDIM / 4; k += 256) Ws4[k] = W4[k];
    int r0 = blockIdx.x * 64;
    for (int idx = t; idx < 64 * FDIM; idx += 256) {
        int k = idx & 127, r = idx >> 7;
        int row = r0 + r;
        Xs[k][r] = (row < N) ? X[(size_t)row * FDIM + k] : 0.0f;
    }
    __syncthreads();
    int tr = t >> 5;      // 0..7  (8 row-groups of 8 rows)
    int tc = t & 31;      // 0..31 (32 col-groups of 4 cols)
    float acc[8][4];
#pragma unroll
    for (int r = 0; r < 8; ++r)
#pragma unroll
        for (int c = 0; c < 4; ++c) acc[r][c] = 0.0f;

    for (int k = 0; k < FDIM; ++k) {
        float4 b = *(const float4*)(Ws + k * FDIM + tc * 4);
        float4 a0 = *(const float4*)(&Xs[k][tr * 8]);
        float4 a1 = *(const float4*)(&Xs[k][tr * 8 + 4]);
        float av[8] = {a0.x, a0.y, a0.z, a0.w, a1.x, a1.y, a1.z, a1.w};
#pragma unroll
        for (int r = 0; r < 8; ++r) {
            acc[r][0] += av[r] * b.x;
            acc[r][1] += av[r] * b.y;
            acc[r][2] += av[r] * b.z;
            acc[r][3] += av[r] * b.w;
        }
    }
#pragma unroll
    for (int r = 0; r < 8; ++r) {
        int row = r0 + tr * 8 + r;
        if (row < N) {
            float4 o = make_float4(acc[r][0], acc[r][1], acc[r][2], acc[r][3]);
            *(float4*)(Y + (size_t)row * FDIM + tc * 4) = o;
        }
    }
}

// ---------------- GATv2 pull: online softmax + aggregate + bias + ELU ----------------
// block = 256 threads = 4 waves; wave w handles node blockIdx*4+w.
// lane l covers channels {2l, 2l+1}; head = l>>5 (channels 2l>=64 <=> l>=32).
__global__ __launch_bounds__(256) void gat_pull_k(const float* __restrict__ xl,
                                                  const float* __restrict__ xr,
                                                  const int* __restrict__ row_ptr,
                                                  const int* __restrict__ srclist,
                                                  const float* __restrict__ att,
                                                  const float* __restrict__ bias,
                                                  float* __restrict__ out, int N) {
    int wid = threadIdx.x >> 6;
    int lane = threadIdx.x & 63;
    int i = blockIdx.x * 4 + wid;
    if (i >= N) return;
    float2 at  = *(const float2*)(att + 2 * lane);
    float2 xrv = *(const float2*)(xr + (size_t)i * FDIM + 2 * lane);
    int beg = row_ptr[i], end = row_ptr[i + 1];
    // two independent online-softmax states (even/odd edges) for ILP
    float m0 = -INFINITY, s0 = 0.f, m1 = -INFINITY, s1 = 0.f;
    float a0x = 0.f, a0y = 0.f, a1x = 0.f, a1y = 0.f;
    int p = beg;
    for (; p + 1 < end; p += 2) {
        int j0 = __builtin_amdgcn_readfirstlane(srclist[p]);
        int j1 = __builtin_amdgcn_readfirstlane(srclist[p + 1]);
        float2 x0 = *(const float2*)(xl + (size_t)j0 * FDIM + 2 * lane);
        float2 x1 = *(const float2*)(xl + (size_t)j1 * FDIM + 2 * lane);
        float l0 = LRELU(xrv.x + x0.x) * at.x + LRELU(xrv.y + x0.y) * at.y;
        float l1 = LRELU(xrv.x + x1.x) * at.x + LRELU(xrv.y + x1.y) * at.y;
        // per-head reduce: masks <32 stay within each 32-lane half (= one head)
        l0 += __shfl_xor(l0, 16, 64); l1 += __shfl_xor(l1, 16, 64);
        l0 += __shfl_xor(l0, 8, 64);  l1 += __shfl_xor(l1, 8, 64);
        l0 += __shfl_xor(l0, 4, 64);  l1 += __shfl_xor(l1, 4, 64);
        l0 += __shfl_xor(l0, 2, 64);  l1 += __shfl_xor(l1, 2, 64);
        l0 += __shfl_xor(l0, 1, 64);  l1 += __shfl_xor(l1, 1, 64);
        float mn0 = fmaxf(m0, l0), sc0 = expf(m0 - mn0), pe0 = expf(l0 - mn0);
        s0 = s0 * sc0 + pe0;
        a0x = a0x * sc0 + pe0 * x0.x; a0y = a0y * sc0 + pe0 * x0.y;
        m0 = mn0;
        float mn1 = fmaxf(m1, l1), sc1 = expf(m1 - mn1), pe1 = expf(l1 - mn1);
        s1 = s1 * sc1 + pe1;
        a1x = a1x * sc1 + pe1 * x1.x; a1y = a1y * sc1 + pe1 * x1.y;
        m1 = mn1;
    }
    if (p < end) {
        int j0 = __builtin_amdgcn_readfirstlane(srclist[p]);
        float2 x0 = *(const float2*)(xl + (size_t)j0 * FDIM + 2 * lane);
        float l0 = LRELU(xrv.x + x0.x) * at.x + LRELU(xrv.y + x0.y) * at.y;
        l0 += __shfl_xor(l0, 16, 64);
        l0 += __shfl_xor(l0, 8, 64);
        l0 += __shfl_xor(l0, 4, 64);
        l0 += __shfl_xor(l0, 2, 64);
        l0 += __shfl_xor(l0, 1, 64);
        float mn0 = fmaxf(m0, l0), sc0 = expf(m0 - mn0), pe0 = expf(l0 - mn0);
        s0 = s0 * sc0 + pe0;
        a0x = a0x * sc0 + pe0 * x0.x; a0y = a0y * sc0 + pe0 * x0.y;
        m0 = mn0;
    }
    // merge the two softmax states (associative segment merge)
    float mn = fmaxf(m0, m1);
    float c0 = (m0 == -INFINITY) ? 0.f : expf(m0 - mn);
    float c1 = (m1 == -INFINITY) ? 0.f : expf(m1 - mn);
    float s = s0 * c0 + s1 * c1 + 1e-16f;
    float rx = (a0x * c0 + a1x * c1) / s;
    float ry = (a0y * c0 + a1y * c1) / s;
    float2 bv = *(const float2*)(bias + 2 * lane);
    float zx = rx + bv.x, zy = ry + bv.y;
    float2 o;
    o.x = (zx > 0.f) ? zx : (expf(zx) - 1.f);
    o.y = (zy > 0.f) ? zy : (expf(zy) - 1.f);
    *(float2*)(out + (size_t)i * FDIM + 2 * lane) = o;
}

// ---------------- label propagation pull step ----------------
__global__ __launch_bounds__(256) void lp_pull_k(const float* __restrict__ y,
                                                 const float* __restrict__ cur,
                                                 float* __restrict__ nxt,
                                                 const int* __restrict__ row_ptr,
                                                 const int* __restrict__ srclist,
                                                 const float* __restrict__ dinv, int N) {
    int wid = threadIdx.x >> 6, lane = threadIdx.x & 63;
    int i = blockIdx.x * 4 + wid;
    if (i >= N) return;
    int beg = row_ptr[i], end = row_ptr[i + 1];
    float ax0 = 0.f, ay0 = 0.f, ax1 = 0.f, ay1 = 0.f;
    int p = beg;
    for (; p + 1 < end; p += 2) {
        int j0 = __builtin_amdgcn_readfirstlane(srclist[p]);
        int j1 = __builtin_amdgcn_readfirstlane(srclist[p + 1]);
        float d0 = dinv[j0], d1 = dinv[j1];
        float2 v0 = *(const float2*)(cur + (size_t)j0 * FDIM + 2 * lane);
        float2 v1 = *(const float2*)(cur + (size_t)j1 * FDIM + 2 * lane);
        ax0 += d0 * v0.x; ay0 += d0 * v0.y;
        ax1 += d1 * v1.x; ay1 += d1 * v1.y;
    }
    if (p < end) {
        int j0 = __builtin_amdgcn_readfirstlane(srclist[p]);
        float d0 = dinv[j0];
        float2 v0 = *(const float2*)(cur + (size_t)j0 * FDIM + 2 * lane);
        ax0 += d0 * v0.x; ay0 += d0 * v0.y;
    }
    float di = dinv[i];
    float2 yv = *(const float2*)(y + (size_t)i * FDIM + 2 * lane);
    float vx = LP_ALPHA * (di * (ax0 + ax1)) + (1.0f - LP_ALPHA) * yv.x;
    float vy = LP_ALPHA * (di * (ay0 + ay1)) + (1.0f - LP_ALPHA) * yv.y;
    float2 o;
    o.x = fminf(fmaxf(vx, 0.f), 1.f);
    o.y = fminf(fmaxf(vy, 0.f), 1.f);
    *(float2*)(nxt + (size_t)i * FDIM + 2 * lane) = o;
}

// ---------------- pooling ----------------
__global__ void count_batch_k(const int* __restrict__ batch, int* __restrict__ gcnt, int N) {
    int n = blockIdx.x * blockDim.x + threadIdx.x;
    if (n >= N) return;
    atomicAdd(&gcnt[batch[n]], 1);
}

__global__ void pool_k(const float* __restrict__ x, const float* __restrict__ h1,
                       const float* __restrict__ h2, const int* __restrict__ batch,
                       float* __restrict__ gsum, int N) {
    __shared__ float ls[NGRAPHS * POOLF]; // 48 KB
    int t = threadIdx.x; // 384
    for (int k = t; k < NGRAPHS * POOLF; k += POOLF) ls[k] = 0.0f;
    __syncthreads();
    const float* srcp = (t < 128) ? x : ((t < 256) ? h1 : h2);
    int f = t & 127;
    int per = (N + gridDim.x - 1) / gridDim.x;
    int n0 = blockIdx.x * per;
    int n1 = min(n0 + per, N);
    for (int n = n0; n < n1; ++n) {
        int b = batch[n];
        ls[b * POOLF + t] += srcp[(size_t)n * FDIM + f];
    }
    __syncthreads();
    for (int k = t; k < NGRAPHS * POOLF; k += POOLF) atomicAdd(&gsum[k], ls[k]);
}

// ---------------- MLP ----------------
__global__ void mlp1_k(const float* __restrict__ gsum, const int* __restrict__ gcnt,
                       const float* __restrict__ W1, const float* __restrict__ b1,
                       float* __restrict__ h) {
    int g = blockIdx.x;     // 32
    int t = threadIdx.x;    // 256
    __shared__ float gm[POOLF];
    float inv = 1.0f / fmaxf((float)gcnt[g], 1.0f);
    for (int k = t; k < POOLF; k += 256) gm[k] = gsum[g * POOLF + k] * inv;
    __syncthreads();
    float acc = b1[t];
    for (int k = 0; k < POOLF; ++k) acc += gm[k] * W1[k * MLP_H + t];
    h[g * MLP_H + t] = fmaxf(acc, 0.0f);
}

__global__ void mlp2_k(const float* __restrict__ h, const float* __restrict__ W2,
                       const float* __restrict__ b2, float* __restrict__ out) {
    int g = blockIdx.x;     // 32
    int t = threadIdx.x;    // 128
    __shared__ float hs[MLP_H];
    for (int k = t; k < MLP_H; k += 128) hs[k] = h[g * MLP_H + k];
    __syncthreads();
    float acc = b2[t];
    for (int k = 0; k < MLP_H; ++k) acc += hs[k] * W2[k * OUT_F + t];
    out[g * OUT_F + t] = acc;
}

// ---------------- launch ----------------
extern "C" void kernel_launch(void* const* d_in, const int* in_sizes, int n_in,
                              void* d_out, int out_size, void* d_ws, size_t ws_size,
                              hipStream_t stream) {
    const float* x    = (const float*)d_in[0];
    const int*   ei   = (const int*)d_in[1];
    const int*   batch= (const int*)d_in[2];
    const float* W_l1 = (const float*)d_in[3];
    const float* W_r1 = (const float*)d_in[4];
    const float* att1 = (const float*)d_in[5];
    const float* b1   = (const float*)d_in[6];
    const float* W_l2 = (const float*)d_in[7];
    const float* W_r2 = (const float*)d_in[8];
    const float* att2 = (const float*)d_in[9];
    const float* b2   = (const float*)d_in[10];
    const float* mW1  = (const float*)d_in[11];
    const float* mb1  = (const float*)d_in[12];
    const float* mW2  = (const float*)d_in[13];
    const float* mb2  = (const float*)d_in[14];
    float* out = (float*)d_out;

    const int N = in_sizes[2];
    const int E = in_sizes[1] / 2;
    const int Esl = E + N;
    const int* src = ei;
    const int* dst = ei + E;

    char* w = (char*)d_ws;
    auto alloc = [&](size_t bytes) -> char* {
        char* p = w;
        w += (bytes + 255) & ~(size_t)255;
        return p;
    };
    float* bufA = (float*)alloc((size_t)N * FDIM * 4);
    float* bufB = (float*)alloc((size_t)N * FDIM * 4);
    float* bufC = (float*)alloc((size_t)N * FDIM * 4);   // h1 lives here
    float* bufD = (float*)alloc((size_t)N * FDIM * 4);   // h2 lives here
    int* deg     = (int*)alloc((size_t)N * 4);
    int* fill_lp = (int*)alloc((size_t)N * 4);
    int* fill_sl = (int*)alloc((size_t)N * 4);
    int* row_lp  = (int*)alloc((size_t)(N + 1) * 4);
    int* row_sl  = (int*)alloc((size_t)(N + 1) * 4);
    int* list_lp = (int*)alloc((size_t)E * 4);
    int* list_sl = (int*)alloc((size_t)Esl * 4);
    float* dinv  = (float*)alloc((size_t)N * 4);
    float* gsum  = (float*)alloc((size_t)NGRAPHS * POOLF * 4);
    int* gcnt    = (int*)alloc((size_t)NGRAPHS * 4);
    float* mlp_h = (float*)alloc((size_t)NGRAPHS * MLP_H * 4);

    const int TB = 256;
    int gE = (E + TB - 1) / TB;
    int gN = (N + TB - 1) / TB;

    // ---- CSR build: one count, one scan, derived self-loop CSR, fused scatter ----
    hipMemsetAsync(deg, 0, (size_t)N * 4, stream);
    hipMemsetAsync(fill_lp, 0, (size_t)N * 4, stream);
    count_deg_k<<<gE, TB, 0, stream>>>(dst, deg, E);
    scan_excl_k<<<1, 1024, 0, stream>>>(deg, row_lp, N);
    node_init_k<<<(N + 1 + TB - 1) / TB, TB, 0, stream>>>(deg, row_lp, row_sl, list_sl,
                                                          fill_sl, dinv, N);
    scatter_both_k<<<gE, TB, 0, stream>>>(src, dst, row_lp, row_sl, fill_lp, fill_sl,
                                          list_lp, list_sl, E);

    int gGemm = (N + 63) / 64;
    int gWave = (N + 3) / 4;   // 4 node-waves per 256-thread block

    // ---- layer 1 ----
    gemm128_k<<<gGemm, 256, 0, stream>>>(x, W_l1, bufA, N);   // xl
    gemm128_k<<<gGemm, 256, 0, stream>>>(x, W_r1, bufB, N);   // xr
    gat_pull_k<<<gWave, 256, 0, stream>>>(bufA, bufB, row_sl, list_sl, att1, b1, bufC, N);
    lp_pull_k<<<gWave, 256, 0, stream>>>(bufC, bufC, bufA, row_lp, list_lp, dinv, N);
    lp_pull_k<<<gWave, 256, 0, stream>>>(bufC, bufA, bufC, row_lp, list_lp, dinv, N);

    // ---- layer 2 ----
    gemm128_k<<<gGemm, 256, 0, stream>>>(bufC, W_l2, bufA, N);
    gemm128_k<<<gGemm, 256, 0, stream>>>(bufC, W_r2, bufB, N);
    gat_pull_k<<<gWave, 256, 0, stream>>>(bufA, bufB, row_sl, list_sl, att2, b2, bufD, N);
    lp_pull_k<<<gWave, 256, 0, stream>>>(bufD, bufD, bufA, row_lp, list_lp, dinv, N);
    lp_pull_k<<<gWave, 256, 0, stream>>>(bufD, bufA, bufD, row_lp, list_lp, dinv, N);

    // ---- pooling ----
    hipMemsetAsync(gsum, 0, (size_t)NGRAPHS * POOLF * 4, stream);
    hipMemsetAsync(gcnt, 0, (size_t)NGRAPHS * 4, stream);
    count_batch_k<<<gN, TB, 0, stream>>>(batch, gcnt, N);
    pool_k<<<64, POOLF, 0, stream>>>(x, bufC, bufD, batch, gsum, N);

    // ---- MLP head ----
    mlp1_k<<<NGRAPHS, 256, 0, stream>>>(gsum, gcnt, mW1, mb1, mlp_h);
    mlp2_k<<<NGRAPHS, 128, 0, stream>>>(mlp_h, mW2, mb2, out);
}

// Round 3
// 1116.184 us; speedup vs baseline: 1.4329x; 1.4329x over previous
//
#include <hip/hip_runtime.h>
#include <math.h>

// ---------------- constants ----------------
#define FDIM 128          // F_IN == HEADS*C_HID == 128
#define NEG_SLOPE 0.2f
#define LP_ALPHA 0.5f
#define NGRAPHS 32
#define POOLF 384         // 3*128
#define MLP_H 256
#define OUT_F 128
#define POOL_CH 8         // chunks per (graph, source) in pooling

#define LRELU(z) ((z) > 0.0f ? (z) : NEG_SLOPE * (z))

// ---------------- CSR build ----------------
__global__ void count_deg_k(const int* __restrict__ dst, int* __restrict__ deg, int E) {
    int e = blockIdx.x * blockDim.x + threadIdx.x;
    if (e < E) atomicAdd(&deg[dst[e]], 1);
}

__global__ void scan_excl_k(const int* __restrict__ deg, int* __restrict__ row_ptr, int n) {
    __shared__ int part[1024];
    int tid = threadIdx.x;
    int chunk = (n + 1023) >> 10;
    int s0 = tid * chunk;
    int s1 = min(s0 + chunk, n);
    int sum = 0;
    for (int i = s0; i < s1; ++i) sum += deg[i];
    part[tid] = sum;
    __syncthreads();
    for (int off = 1; off < 1024; off <<= 1) {
        int v = (tid >= off) ? part[tid - off] : 0;
        __syncthreads();
        part[tid] += v;
        __syncthreads();
    }
    int run = (tid == 0) ? 0 : part[tid - 1];
    for (int i = s0; i < s1; ++i) { row_ptr[i] = run; run += deg[i]; }
    if (tid == 1023) row_ptr[n] = part[1023];
}

// derive self-loop CSR offsets (each node contributes exactly 1 self-loop),
// seed the self-loop entry first, init fill counters and dinv.
__global__ void node_init_k(const int* __restrict__ deg, const int* __restrict__ row_lp,
                            int* __restrict__ row_sl, int* __restrict__ list_sl,
                            int* __restrict__ fill_sl, float* __restrict__ dinv, int N) {
    int i = blockIdx.x * blockDim.x + threadIdx.x;
    if (i > N) return;
    if (i == N) { row_sl[N] = row_lp[N] + N; return; }
    int rs = row_lp[i] + i;
    row_sl[i] = rs;
    list_sl[rs] = i;          // self-loop first in each segment
    fill_sl[i] = 1;
    int d = deg[i];
    dinv[i] = (d > 0) ? (1.0f / sqrtf((float)d)) : 0.0f;
}

// one pass fills both adjacency lists (stores SOURCE node ids, grouped by dst)
__global__ void scatter_both_k(const int* __restrict__ src, const int* __restrict__ dst,
                               const int* __restrict__ row_lp, const int* __restrict__ row_sl,
                               int* __restrict__ fill_lp, int* __restrict__ fill_sl,
                               int* __restrict__ list_lp, int* __restrict__ list_sl, int E) {
    int e = blockIdx.x * blockDim.x + threadIdx.x;
    if (e >= E) return;
    int d = dst[e], s = src[e];
    int p1 = atomicAdd(&fill_lp[d], 1);
    list_lp[row_lp[d] + p1] = s;
    int p2 = atomicAdd(&fill_sl[d], 1);
    list_sl[row_sl[d] + p2] = s;
}

// ---------------- graph boundaries: batch is SORTED -> binary search ----------------
__global__ void gbound_k(const int* __restrict__ batch, int* __restrict__ gb, int N) {
    int g = threadIdx.x;             // 0..NGRAPHS
    if (g > NGRAPHS) return;
    int lo = 0, hi = N;              // first index with batch[i] >= g
    while (lo < hi) {
        int mid = (lo + hi) >> 1;
        if (batch[mid] < g) lo = mid + 1; else hi = mid;
    }
    gb[g] = lo;
}

// ---------------- node GEMM: Y[N,128] = X[N,128] @ W[128,128] ----------------
// 64 rows x 128 cols per block, 256 threads, 8x4 register tile per thread.
__global__ __launch_bounds__(256) void gemm128_k(const float* __restrict__ X,
                                                 const float* __restrict__ W,
                                                 float* __restrict__ Y, int N) {
    __shared__ float Ws[FDIM * FDIM];     // 64 KB, [k][col]
    __shared__ float Xs[FDIM][68];        // 34 KB, transposed [k][r], padded
    int t = threadIdx.x;
    const float4* W4 = (const float4*)W;
    float4* Ws4 = (float4*)Ws;
    for (int k = t; k < FDIM * FDIM / 4; k += 256) Ws4[k] = W4[k];
    int r0 = blockIdx.x * 64;
    for (int idx = t; idx < 64 * FDIM; idx += 256) {
        int k = idx & 127, r = idx >> 7;
        int row = r0 + r;
        Xs[k][r] = (row < N) ? X[(size_t)row * FDIM + k] : 0.0f;
    }
    __syncthreads();
    int tr = t >> 5;      // 0..7  (8 row-groups of 8 rows)
    int tc = t & 31;      // 0..31 (32 col-groups of 4 cols)
    float acc[8][4];
#pragma unroll
    for (int r = 0; r < 8; ++r)
#pragma unroll
        for (int c = 0; c < 4; ++c) acc[r][c] = 0.0f;

    for (int k = 0; k < FDIM; ++k) {
        float4 b = *(const float4*)(Ws + k * FDIM + tc * 4);
        float4 a0 = *(const float4*)(&Xs[k][tr * 8]);
        float4 a1 = *(const float4*)(&Xs[k][tr * 8 + 4]);
        float av[8] = {a0.x, a0.y, a0.z, a0.w, a1.x, a1.y, a1.z, a1.w};
#pragma unroll
        for (int r = 0; r < 8; ++r) {
            acc[r][0] += av[r] * b.x;
            acc[r][1] += av[r] * b.y;
            acc[r][2] += av[r] * b.z;
            acc[r][3] += av[r] * b.w;
        }
    }
#pragma unroll
    for (int r = 0; r < 8; ++r) {
        int row = r0 + tr * 8 + r;
        if (row < N) {
            float4 o = make_float4(acc[r][0], acc[r][1], acc[r][2], acc[r][3]);
            *(float4*)(Y + (size_t)row * FDIM + tc * 4) = o;
        }
    }
}

// ---------------- GATv2 pull: online softmax + aggregate + bias + ELU ----------------
// block = 256 threads = 4 waves; wave w handles node blockIdx*4+w.
// lane l covers channels {2l, 2l+1}; head = l>>5.
__global__ __launch_bounds__(256) void gat_pull_k(const float* __restrict__ xl,
                                                  const float* __restrict__ xr,
                                                  const int* __restrict__ row_ptr,
                                                  const int* __restrict__ srclist,
                                                  const float* __restrict__ att,
                                                  const float* __restrict__ bias,
                                                  float* __restrict__ out, int N) {
    int wid = threadIdx.x >> 6;
    int lane = threadIdx.x & 63;
    int i = blockIdx.x * 4 + wid;
    if (i >= N) return;
    float2 at  = *(const float2*)(att + 2 * lane);
    float2 xrv = *(const float2*)(xr + (size_t)i * FDIM + 2 * lane);
    int beg = row_ptr[i], end = row_ptr[i + 1];
    // two independent online-softmax states (even/odd edges) for ILP
    float m0 = -INFINITY, s0 = 0.f, m1 = -INFINITY, s1 = 0.f;
    float a0x = 0.f, a0y = 0.f, a1x = 0.f, a1y = 0.f;
    int p = beg;
    for (; p + 1 < end; p += 2) {
        int j0 = __builtin_amdgcn_readfirstlane(srclist[p]);
        int j1 = __builtin_amdgcn_readfirstlane(srclist[p + 1]);
        float2 x0 = *(const float2*)(xl + (size_t)j0 * FDIM + 2 * lane);
        float2 x1 = *(const float2*)(xl + (size_t)j1 * FDIM + 2 * lane);
        float l0 = LRELU(xrv.x + x0.x) * at.x + LRELU(xrv.y + x0.y) * at.y;
        float l1 = LRELU(xrv.x + x1.x) * at.x + LRELU(xrv.y + x1.y) * at.y;
        // per-head reduce: masks <32 stay within each 32-lane half (= one head)
        l0 += __shfl_xor(l0, 16, 64); l1 += __shfl_xor(l1, 16, 64);
        l0 += __shfl_xor(l0, 8, 64);  l1 += __shfl_xor(l1, 8, 64);
        l0 += __shfl_xor(l0, 4, 64);  l1 += __shfl_xor(l1, 4, 64);
        l0 += __shfl_xor(l0, 2, 64);  l1 += __shfl_xor(l1, 2, 64);
        l0 += __shfl_xor(l0, 1, 64);  l1 += __shfl_xor(l1, 1, 64);
        float mn0 = fmaxf(m0, l0), sc0 = expf(m0 - mn0), pe0 = expf(l0 - mn0);
        s0 = s0 * sc0 + pe0;
        a0x = a0x * sc0 + pe0 * x0.x; a0y = a0y * sc0 + pe0 * x0.y;
        m0 = mn0;
        float mn1 = fmaxf(m1, l1), sc1 = expf(m1 - mn1), pe1 = expf(l1 - mn1);
        s1 = s1 * sc1 + pe1;
        a1x = a1x * sc1 + pe1 * x1.x; a1y = a1y * sc1 + pe1 * x1.y;
        m1 = mn1;
    }
    if (p < end) {
        int j0 = __builtin_amdgcn_readfirstlane(srclist[p]);
        float2 x0 = *(const float2*)(xl + (size_t)j0 * FDIM + 2 * lane);
        float l0 = LRELU(xrv.x + x0.x) * at.x + LRELU(xrv.y + x0.y) * at.y;
        l0 += __shfl_xor(l0, 16, 64);
        l0 += __shfl_xor(l0, 8, 64);
        l0 += __shfl_xor(l0, 4, 64);
        l0 += __shfl_xor(l0, 2, 64);
        l0 += __shfl_xor(l0, 1, 64);
        float mn0 = fmaxf(m0, l0), sc0 = expf(m0 - mn0), pe0 = expf(l0 - mn0);
        s0 = s0 * sc0 + pe0;
        a0x = a0x * sc0 + pe0 * x0.x; a0y = a0y * sc0 + pe0 * x0.y;
        m0 = mn0;
    }
    // merge the two softmax states (associative segment merge)
    float mn = fmaxf(m0, m1);
    float c0 = (m0 == -INFINITY) ? 0.f : expf(m0 - mn);
    float c1 = (m1 == -INFINITY) ? 0.f : expf(m1 - mn);
    float s = s0 * c0 + s1 * c1 + 1e-16f;
    float rx = (a0x * c0 + a1x * c1) / s;
    float ry = (a0y * c0 + a1y * c1) / s;
    float2 bv = *(const float2*)(bias + 2 * lane);
    float zx = rx + bv.x, zy = ry + bv.y;
    float2 o;
    o.x = (zx > 0.f) ? zx : (expf(zx) - 1.f);
    o.y = (zy > 0.f) ? zy : (expf(zy) - 1.f);
    *(float2*)(out + (size_t)i * FDIM + 2 * lane) = o;
}

// ---------------- label propagation pull step (unroll-4 gathers) ----------------
__global__ __launch_bounds__(256) void lp_pull_k(const float* __restrict__ y,
                                                 const float* __restrict__ cur,
                                                 float* __restrict__ nxt,
                                                 const int* __restrict__ row_ptr,
                                                 const int* __restrict__ srclist,
                                                 const float* __restrict__ dinv, int N) {
    int wid = threadIdx.x >> 6, lane = threadIdx.x & 63;
    int i = blockIdx.x * 4 + wid;
    if (i >= N) return;
    int beg = row_ptr[i], end = row_ptr[i + 1];
    float ax0 = 0.f, ay0 = 0.f, ax1 = 0.f, ay1 = 0.f;
    float ax2 = 0.f, ay2 = 0.f, ax3 = 0.f, ay3 = 0.f;
    int p = beg;
    for (; p + 3 < end; p += 4) {
        int j0 = __builtin_amdgcn_readfirstlane(srclist[p]);
        int j1 = __builtin_amdgcn_readfirstlane(srclist[p + 1]);
        int j2 = __builtin_amdgcn_readfirstlane(srclist[p + 2]);
        int j3 = __builtin_amdgcn_readfirstlane(srclist[p + 3]);
        float d0 = dinv[j0], d1 = dinv[j1], d2 = dinv[j2], d3 = dinv[j3];
        float2 v0 = *(const float2*)(cur + (size_t)j0 * FDIM + 2 * lane);
        float2 v1 = *(const float2*)(cur + (size_t)j1 * FDIM + 2 * lane);
        float2 v2 = *(const float2*)(cur + (size_t)j2 * FDIM + 2 * lane);
        float2 v3 = *(const float2*)(cur + (size_t)j3 * FDIM + 2 * lane);
        ax0 += d0 * v0.x; ay0 += d0 * v0.y;
        ax1 += d1 * v1.x; ay1 += d1 * v1.y;
        ax2 += d2 * v2.x; ay2 += d2 * v2.y;
        ax3 += d3 * v3.x; ay3 += d3 * v3.y;
    }
    for (; p < end; ++p) {
        int j0 = __builtin_amdgcn_readfirstlane(srclist[p]);
        float d0 = dinv[j0];
        float2 v0 = *(const float2*)(cur + (size_t)j0 * FDIM + 2 * lane);
        ax0 += d0 * v0.x; ay0 += d0 * v0.y;
    }
    float di = dinv[i];
    float2 yv = *(const float2*)(y + (size_t)i * FDIM + 2 * lane);
    float vx = LP_ALPHA * (di * ((ax0 + ax1) + (ax2 + ax3))) + (1.0f - LP_ALPHA) * yv.x;
    float vy = LP_ALPHA * (di * ((ay0 + ay1) + (ay2 + ay3))) + (1.0f - LP_ALPHA) * yv.y;
    float2 o;
    o.x = fminf(fmaxf(vx, 0.f), 1.f);
    o.y = fminf(fmaxf(vy, 0.f), 1.f);
    *(float2*)(nxt + (size_t)i * FDIM + 2 * lane) = o;
}

// ---------------- pooling: segmented (batch sorted), atomic-free ----------------
// grid (NGRAPHS, 3 sources, POOL_CH chunks), block 128. Partials to ws.
__global__ void pool_part_k(const float* __restrict__ x, const float* __restrict__ h1,
                            const float* __restrict__ h2, const int* __restrict__ gb,
                            float* __restrict__ part) {
    int g = blockIdx.x, si = blockIdx.y, ch = blockIdx.z;
    int t = threadIdx.x; // 128
    const float* s = (si == 0) ? x : ((si == 1) ? h1 : h2);
    int n0g = gb[g], n1g = gb[g + 1];
    int len = n1g - n0g;
    int per = (len + POOL_CH - 1) / POOL_CH;
    int n0 = n0g + ch * per;
    int n1 = min(n0 + per, n1g);
    float acc = 0.0f;
    for (int n = n0; n < n1; ++n) acc += s[(size_t)n * FDIM + t];
    part[(((g * 3 + si) << 3) + ch) * FDIM + t] = acc;
}

// ---------------- MLP ----------------
__global__ void mlp1_k(const float* __restrict__ part, const int* __restrict__ gb,
                       const float* __restrict__ W1, const float* __restrict__ b1,
                       float* __restrict__ h) {
    int g = blockIdx.x;     // 32
    int t = threadIdx.x;    // 256
    __shared__ float gm[POOLF];
    int cnt = gb[g + 1] - gb[g];
    float inv = 1.0f / fmaxf((float)cnt, 1.0f);
    for (int f = t; f < POOLF; f += 256) {
        int si = f >> 7, fl = f & 127;
        float s = 0.0f;
#pragma unroll
        for (int c = 0; c < POOL_CH; ++c)
            s += part[(((g * 3 + si) << 3) + c) * FDIM + fl];
        gm[f] = s * inv;
    }
    __syncthreads();
    float acc = b1[t];
    for (int k = 0; k < POOLF; ++k) acc += gm[k] * W1[k * MLP_H + t];
    h[g * MLP_H + t] = fmaxf(acc, 0.0f);
}

__global__ void mlp2_k(const float* __restrict__ h, const float* __restrict__ W2,
                       const float* __restrict__ b2, float* __restrict__ out) {
    int g = blockIdx.x;     // 32
    int t = threadIdx.x;    // 128
    __shared__ float hs[MLP_H];
    for (int k = t; k < MLP_H; k += 128) hs[k] = h[g * MLP_H + k];
    __syncthreads();
    float acc = b2[t];
    for (int k = 0; k < MLP_H; ++k) acc += hs[k] * W2[k * OUT_F + t];
    out[g * OUT_F + t] = acc;
}

// ---------------- launch ----------------
extern "C" void kernel_launch(void* const* d_in, const int* in_sizes, int n_in,
                              void* d_out, int out_size, void* d_ws, size_t ws_size,
                              hipStream_t stream) {
    const float* x    = (const float*)d_in[0];
    const int*   ei   = (const int*)d_in[1];
    const int*   batch= (const int*)d_in[2];
    const float* W_l1 = (const float*)d_in[3];
    const float* W_r1 = (const float*)d_in[4];
    const float* att1 = (const float*)d_in[5];
    const float* b1   = (const float*)d_in[6];
    const float* W_l2 = (const float*)d_in[7];
    const float* W_r2 = (const float*)d_in[8];
    const float* att2 = (const float*)d_in[9];
    const float* b2   = (const float*)d_in[10];
    const float* mW1  = (const float*)d_in[11];
    const float* mb1  = (const float*)d_in[12];
    const float* mW2  = (const float*)d_in[13];
    const float* mb2  = (const float*)d_in[14];
    float* out = (float*)d_out;

    const int N = in_sizes[2];
    const int E = in_sizes[1] / 2;
    const int Esl = E + N;
    const int* src = ei;
    const int* dst = ei + E;

    char* w = (char*)d_ws;
    auto alloc = [&](size_t bytes) -> char* {
        char* p = w;
        w += (bytes + 255) & ~(size_t)255;
        return p;
    };
    float* bufA = (float*)alloc((size_t)N * FDIM * 4);
    float* bufB = (float*)alloc((size_t)N * FDIM * 4);
    float* bufC = (float*)alloc((size_t)N * FDIM * 4);   // h1 lives here
    float* bufD = (float*)alloc((size_t)N * FDIM * 4);   // h2 lives here
    int* deg     = (int*)alloc((size_t)N * 4);
    int* fill_lp = (int*)alloc((size_t)N * 4);
    int* fill_sl = (int*)alloc((size_t)N * 4);
    int* row_lp  = (int*)alloc((size_t)(N + 1) * 4);
    int* row_sl  = (int*)alloc((size_t)(N + 1) * 4);
    int* list_lp = (int*)alloc((size_t)E * 4);
    int* list_sl = (int*)alloc((size_t)Esl * 4);
    float* dinv  = (float*)alloc((size_t)N * 4);
    int* gb      = (int*)alloc((size_t)(NGRAPHS + 1) * 4);
    float* part  = (float*)alloc((size_t)NGRAPHS * 3 * POOL_CH * FDIM * 4);
    float* mlp_h = (float*)alloc((size_t)NGRAPHS * MLP_H * 4);

    const int TB = 256;
    int gE = (E + TB - 1) / TB;

    // ---- CSR build: one count, one scan, derived self-loop CSR, fused scatter ----
    hipMemsetAsync(deg, 0, (size_t)N * 4, stream);
    hipMemsetAsync(fill_lp, 0, (size_t)N * 4, stream);
    count_deg_k<<<gE, TB, 0, stream>>>(dst, deg, E);
    gbound_k<<<1, 64, 0, stream>>>(batch, gb, N);   // graph boundaries (batch sorted)
    scan_excl_k<<<1, 1024, 0, stream>>>(deg, row_lp, N);
    node_init_k<<<(N + 1 + TB - 1) / TB, TB, 0, stream>>>(deg, row_lp, row_sl, list_sl,
                                                          fill_sl, dinv, N);
    scatter_both_k<<<gE, TB, 0, stream>>>(src, dst, row_lp, row_sl, fill_lp, fill_sl,
                                          list_lp, list_sl, E);

    int gGemm = (N + 63) / 64;
    int gWave = (N + 3) / 4;   // 4 node-waves per 256-thread block

    // ---- layer 1 ----
    gemm128_k<<<gGemm, 256, 0, stream>>>(x, W_l1, bufA, N);   // xl
    gemm128_k<<<gGemm, 256, 0, stream>>>(x, W_r1, bufB, N);   // xr
    gat_pull_k<<<gWave, 256, 0, stream>>>(bufA, bufB, row_sl, list_sl, att1, b1, bufC, N);
    lp_pull_k<<<gWave, 256, 0, stream>>>(bufC, bufC, bufA, row_lp, list_lp, dinv, N);
    lp_pull_k<<<gWave, 256, 0, stream>>>(bufC, bufA, bufC, row_lp, list_lp, dinv, N);

    // ---- layer 2 ----
    gemm128_k<<<gGemm, 256, 0, stream>>>(bufC, W_l2, bufA, N);
    gemm128_k<<<gGemm, 256, 0, stream>>>(bufC, W_r2, bufB, N);
    gat_pull_k<<<gWave, 256, 0, stream>>>(bufA, bufB, row_sl, list_sl, att2, b2, bufD, N);
    lp_pull_k<<<gWave, 256, 0, stream>>>(bufD, bufD, bufA, row_lp, list_lp, dinv, N);
    lp_pull_k<<<gWave, 256, 0, stream>>>(bufD, bufA, bufD, row_lp, list_lp, dinv, N);

    // ---- pooling (segmented, atomic-free) ----
    pool_part_k<<<dim3(NGRAPHS, 3, POOL_CH), 128, 0, stream>>>(x, bufC, bufD, gb, part);

    // ---- MLP head ----
    mlp1_k<<<NGRAPHS, 256, 0, stream>>>(part, gb, mW1, mb1, mlp_h);
    mlp2_k<<<NGRAPHS, 128, 0, stream>>>(mlp_h, mW2, mb2, out);
}

// Round 4
// 863.286 us; speedup vs baseline: 1.8527x; 1.2929x over previous
//
#include <hip/hip_runtime.h>
#include <math.h>

// ---------------- constants ----------------
#define FDIM 128          // F_IN == HEADS*C_HID == 128
#define NEG_SLOPE 0.2f
#define LP_ALPHA 0.5f
#define NGRAPHS 32
#define POOLF 384         // 3*128
#define MLP_H 256
#define OUT_F 128
#define POOL_CH 8         // chunks per (graph, source) in pooling

#define LRELU(z) ((z) > 0.0f ? (z) : NEG_SLOPE * (z))
#define RFL(v) __builtin_amdgcn_readfirstlane(v)

// ---------------- CSR build ----------------
__global__ void count_deg_k(const int* __restrict__ dst, int* __restrict__ deg, int E) {
    int e = blockIdx.x * blockDim.x + threadIdx.x;
    if (e < E) atomicAdd(&deg[dst[e]], 1);
}

__global__ void scan_excl_k(const int* __restrict__ deg, int* __restrict__ row_ptr, int n) {
    __shared__ int part[1024];
    int tid = threadIdx.x;
    int chunk = (n + 1023) >> 10;
    int s0 = tid * chunk;
    int s1 = min(s0 + chunk, n);
    int sum = 0;
    for (int i = s0; i < s1; ++i) sum += deg[i];
    part[tid] = sum;
    __syncthreads();
    for (int off = 1; off < 1024; off <<= 1) {
        int v = (tid >= off) ? part[tid - off] : 0;
        __syncthreads();
        part[tid] += v;
        __syncthreads();
    }
    int run = (tid == 0) ? 0 : part[tid - 1];
    for (int i = s0; i < s1; ++i) { row_ptr[i] = run; run += deg[i]; }
    if (tid == 1023) row_ptr[n] = part[1023];
}

__global__ void dinv_k(const int* __restrict__ deg, float* __restrict__ dinv, int N) {
    int i = blockIdx.x * blockDim.x + threadIdx.x;
    if (i < N) {
        int d = deg[i];
        dinv[i] = (d > 0) ? (1.0f / sqrtf((float)d)) : 0.0f;
    }
}

// one random 8B store per edge: {src, dinv[src]} packed (halves write amplification
// vs two 4B stores to two lists; self-loops are folded into gat_pull directly)
__global__ void scatter_k(const int* __restrict__ src, const int* __restrict__ dst,
                          const int* __restrict__ row_ptr, int* __restrict__ fill,
                          const float* __restrict__ dinv, int2* __restrict__ elist, int E) {
    int e = blockIdx.x * blockDim.x + threadIdx.x;
    if (e >= E) return;
    int d = dst[e], s = src[e];
    int pos = atomicAdd(&fill[d], 1);
    elist[row_ptr[d] + pos] = make_int2(s, __float_as_int(dinv[s]));
}

// ---------------- graph boundaries: batch is SORTED -> binary search ----------------
__global__ void gbound_k(const int* __restrict__ batch, int* __restrict__ gb, int N) {
    int g = threadIdx.x;             // 0..NGRAPHS
    if (g > NGRAPHS) return;
    int lo = 0, hi = N;              // first index with batch[i] >= g
    while (lo < hi) {
        int mid = (lo + hi) >> 1;
        if (batch[mid] < g) lo = mid + 1; else hi = mid;
    }
    gb[g] = lo;
}

// ---------------- node GEMM: Y[N,128] = X[N,128] @ W[128,128] ----------------
// 64 rows x 128 cols per block, 256 threads, 8x4 register tile.
// Only X (transposed) in LDS (34 KB -> 4 blocks/CU); W read via L1/L2 (shared by all blocks).
__global__ __launch_bounds__(256) void gemm128_k(const float* __restrict__ X,
                                                 const float* __restrict__ W,
                                                 float* __restrict__ Y, int N) {
    __shared__ float Xs[FDIM][68];        // [k][r], padded, rows 16B-aligned
    int t = threadIdx.x;
    int r0 = blockIdx.x * 64;
    for (int idx = t; idx < 64 * FDIM; idx += 256) {
        int k = idx & 127, r = idx >> 7;
        int row = r0 + r;
        Xs[k][r] = (row < N) ? X[(size_t)row * FDIM + k] : 0.0f;
    }
    __syncthreads();
    int tr = t >> 5;      // 0..7  (8 row-groups of 8 rows)
    int tc = t & 31;      // 0..31 (32 col-groups of 4 cols)
    float acc[8][4];
#pragma unroll
    for (int r = 0; r < 8; ++r)
#pragma unroll
        for (int c = 0; c < 4; ++c) acc[r][c] = 0.0f;

#pragma unroll 2
    for (int k = 0; k < FDIM; ++k) {
        float4 b = *(const float4*)(W + k * FDIM + tc * 4);   // L1/L2-resident
        float4 a0 = *(const float4*)(&Xs[k][tr * 8]);
        float4 a1 = *(const float4*)(&Xs[k][tr * 8 + 4]);
        float av[8] = {a0.x, a0.y, a0.z, a0.w, a1.x, a1.y, a1.z, a1.w};
#pragma unroll
        for (int r = 0; r < 8; ++r) {
            acc[r][0] = fmaf(av[r], b.x, acc[r][0]);
            acc[r][1] = fmaf(av[r], b.y, acc[r][1]);
            acc[r][2] = fmaf(av[r], b.z, acc[r][2]);
            acc[r][3] = fmaf(av[r], b.w, acc[r][3]);
        }
    }
#pragma unroll
    for (int r = 0; r < 8; ++r) {
        int row = r0 + tr * 8 + r;
        if (row < N) {
            float4 o = make_float4(acc[r][0], acc[r][1], acc[r][2], acc[r][3]);
            *(float4*)(Y + (size_t)row * FDIM + tc * 4) = o;
        }
    }
}

// ---------------- GATv2 pull: online softmax + aggregate + bias + ELU ----------------
// block = 256 = 4 waves; wave handles one node. lane covers channels {2l,2l+1}; head = l>>5.
// Self-loop folded in (seeds softmax state0); edges from elist (.x = src).
// __expf (native v_exp) replaces libm expf -> ~2.3x less VALU per edge.
__global__ __launch_bounds__(256) void gat_pull_k(const float* __restrict__ xl,
                                                  const float* __restrict__ xr,
                                                  const int* __restrict__ row_ptr,
                                                  const int2* __restrict__ elist,
                                                  const float* __restrict__ att,
                                                  const float* __restrict__ bias,
                                                  float* __restrict__ out, int N) {
    int wid = threadIdx.x >> 6;
    int lane = threadIdx.x & 63;
    int i = blockIdx.x * 4 + wid;
    if (i >= N) return;
    float2 at  = *(const float2*)(att + 2 * lane);
    size_t ibase = (size_t)i * FDIM + 2 * lane;
    float2 xrv   = *(const float2*)(xr + ibase);
    float2 xself = *(const float2*)(xl + ibase);

    auto hred = [](float v) {  // sum over the 32 lanes of this head
        v += __shfl_xor(v, 16, 64);
        v += __shfl_xor(v, 8, 64);
        v += __shfl_xor(v, 4, 64);
        v += __shfl_xor(v, 2, 64);
        v += __shfl_xor(v, 1, 64);
        return v;
    };

    // self-loop seeds state0
    float lself = hred(LRELU(xrv.x + xself.x) * at.x + LRELU(xrv.y + xself.y) * at.y);
    float m0 = lself, s0 = 1.0f, a0x = xself.x, a0y = xself.y;
    float m1 = -INFINITY, s1 = 0.0f, a1x = 0.0f, a1y = 0.0f;

    int beg = row_ptr[i], end = row_ptr[i + 1];
    int p = beg;
    for (; p + 3 < end; p += 4) {
        int j0 = RFL(elist[p].x);
        int j1 = RFL(elist[p + 1].x);
        int j2 = RFL(elist[p + 2].x);
        int j3 = RFL(elist[p + 3].x);
        float2 x0 = *(const float2*)(xl + (size_t)j0 * FDIM + 2 * lane);
        float2 x1 = *(const float2*)(xl + (size_t)j1 * FDIM + 2 * lane);
        float2 x2 = *(const float2*)(xl + (size_t)j2 * FDIM + 2 * lane);
        float2 x3 = *(const float2*)(xl + (size_t)j3 * FDIM + 2 * lane);
        float l0 = hred(LRELU(xrv.x + x0.x) * at.x + LRELU(xrv.y + x0.y) * at.y);
        float l1 = hred(LRELU(xrv.x + x1.x) * at.x + LRELU(xrv.y + x1.y) * at.y);
        float l2 = hred(LRELU(xrv.x + x2.x) * at.x + LRELU(xrv.y + x2.y) * at.y);
        float l3 = hred(LRELU(xrv.x + x3.x) * at.x + LRELU(xrv.y + x3.y) * at.y);
        { float mn = fmaxf(m0, l0); float sc = __expf(m0 - mn), pe = __expf(l0 - mn);
          s0 = fmaf(s0, sc, pe); a0x = fmaf(a0x, sc, pe * x0.x); a0y = fmaf(a0y, sc, pe * x0.y); m0 = mn; }
        { float mn = fmaxf(m1, l1); float sc = __expf(m1 - mn), pe = __expf(l1 - mn);
          s1 = fmaf(s1, sc, pe); a1x = fmaf(a1x, sc, pe * x1.x); a1y = fmaf(a1y, sc, pe * x1.y); m1 = mn; }
        { float mn = fmaxf(m0, l2); float sc = __expf(m0 - mn), pe = __expf(l2 - mn);
          s0 = fmaf(s0, sc, pe); a0x = fmaf(a0x, sc, pe * x2.x); a0y = fmaf(a0y, sc, pe * x2.y); m0 = mn; }
        { float mn = fmaxf(m1, l3); float sc = __expf(m1 - mn), pe = __expf(l3 - mn);
          s1 = fmaf(s1, sc, pe); a1x = fmaf(a1x, sc, pe * x3.x); a1y = fmaf(a1y, sc, pe * x3.y); m1 = mn; }
    }
    for (; p < end; ++p) {
        int j0 = RFL(elist[p].x);
        float2 x0 = *(const float2*)(xl + (size_t)j0 * FDIM + 2 * lane);
        float l0 = hred(LRELU(xrv.x + x0.x) * at.x + LRELU(xrv.y + x0.y) * at.y);
        float mn = fmaxf(m0, l0); float sc = __expf(m0 - mn), pe = __expf(l0 - mn);
        s0 = fmaf(s0, sc, pe); a0x = fmaf(a0x, sc, pe * x0.x); a0y = fmaf(a0y, sc, pe * x0.y); m0 = mn;
    }
    // merge the two softmax states (associative segment merge); m0 always finite
    float mn = fmaxf(m0, m1);
    float c0 = __expf(m0 - mn);
    float c1 = (m1 == -INFINITY) ? 0.0f : __expf(m1 - mn);
    float s = fmaf(s0, c0, s1 * c1) + 1e-16f;
    float rx = (a0x * c0 + a1x * c1) / s;
    float ry = (a0y * c0 + a1y * c1) / s;
    float2 bv = *(const float2*)(bias + 2 * lane);
    float zx = rx + bv.x, zy = ry + bv.y;
    float2 o;
    o.x = (zx > 0.0f) ? zx : (__expf(zx) - 1.0f);
    o.y = (zy > 0.0f) ? zy : (__expf(zy) - 1.0f);
    *(float2*)(out + ibase) = o;
}

// ---------------- label propagation pull step (unroll-8, packed edge weights) ----------------
__global__ __launch_bounds__(256) void lp_pull_k(const float* __restrict__ y,
                                                 const float* __restrict__ cur,
                                                 float* __restrict__ nxt,
                                                 const int* __restrict__ row_ptr,
                                                 const int2* __restrict__ elist,
                                                 const float* __restrict__ dinv, int N) {
    int wid = threadIdx.x >> 6, lane = threadIdx.x & 63;
    int i = blockIdx.x * 4 + wid;
    if (i >= N) return;
    int beg = row_ptr[i], end = row_ptr[i + 1];
    float ax0 = 0.f, ay0 = 0.f, ax1 = 0.f, ay1 = 0.f;
    float ax2 = 0.f, ay2 = 0.f, ax3 = 0.f, ay3 = 0.f;
    float ax4 = 0.f, ay4 = 0.f, ax5 = 0.f, ay5 = 0.f;
    float ax6 = 0.f, ay6 = 0.f, ax7 = 0.f, ay7 = 0.f;
    int p = beg;
    for (; p + 7 < end; p += 8) {
        int2 e0 = elist[p + 0], e1 = elist[p + 1], e2 = elist[p + 2], e3 = elist[p + 3];
        int2 e4 = elist[p + 4], e5 = elist[p + 5], e6 = elist[p + 6], e7 = elist[p + 7];
        int j0 = RFL(e0.x); float w0 = __int_as_float(RFL(e0.y));
        int j1 = RFL(e1.x); float w1 = __int_as_float(RFL(e1.y));
        int j2 = RFL(e2.x); float w2 = __int_as_float(RFL(e2.y));
        int j3 = RFL(e3.x); float w3 = __int_as_float(RFL(e3.y));
        int j4 = RFL(e4.x); float w4 = __int_as_float(RFL(e4.y));
        int j5 = RFL(e5.x); float w5 = __int_as_float(RFL(e5.y));
        int j6 = RFL(e6.x); float w6 = __int_as_float(RFL(e6.y));
        int j7 = RFL(e7.x); float w7 = __int_as_float(RFL(e7.y));
        float2 v0 = *(const float2*)(cur + (size_t)j0 * FDIM + 2 * lane);
        float2 v1 = *(const float2*)(cur + (size_t)j1 * FDIM + 2 * lane);
        float2 v2 = *(const float2*)(cur + (size_t)j2 * FDIM + 2 * lane);
        float2 v3 = *(const float2*)(cur + (size_t)j3 * FDIM + 2 * lane);
        float2 v4 = *(const float2*)(cur + (size_t)j4 * FDIM + 2 * lane);
        float2 v5 = *(const float2*)(cur + (size_t)j5 * FDIM + 2 * lane);
        float2 v6 = *(const float2*)(cur + (size_t)j6 * FDIM + 2 * lane);
        float2 v7 = *(const float2*)(cur + (size_t)j7 * FDIM + 2 * lane);
        ax0 = fmaf(w0, v0.x, ax0); ay0 = fmaf(w0, v0.y, ay0);
        ax1 = fmaf(w1, v1.x, ax1); ay1 = fmaf(w1, v1.y, ay1);
        ax2 = fmaf(w2, v2.x, ax2); ay2 = fmaf(w2, v2.y, ay2);
        ax3 = fmaf(w3, v3.x, ax3); ay3 = fmaf(w3, v3.y, ay3);
        ax4 = fmaf(w4, v4.x, ax4); ay4 = fmaf(w4, v4.y, ay4);
        ax5 = fmaf(w5, v5.x, ax5); ay5 = fmaf(w5, v5.y, ay5);
        ax6 = fmaf(w6, v6.x, ax6); ay6 = fmaf(w6, v6.y, ay6);
        ax7 = fmaf(w7, v7.x, ax7); ay7 = fmaf(w7, v7.y, ay7);
    }
    for (; p < end; ++p) {
        int2 e0 = elist[p];
        int j0 = RFL(e0.x); float w0 = __int_as_float(RFL(e0.y));
        float2 v0 = *(const float2*)(cur + (size_t)j0 * FDIM + 2 * lane);
        ax0 = fmaf(w0, v0.x, ax0); ay0 = fmaf(w0, v0.y, ay0);
    }
    float sx = ((ax0 + ax1) + (ax2 + ax3)) + ((ax4 + ax5) + (ax6 + ax7));
    float sy = ((ay0 + ay1) + (ay2 + ay3)) + ((ay4 + ay5) + (ay6 + ay7));
    float di = dinv[i];
    float2 yv = *(const float2*)(y + (size_t)i * FDIM + 2 * lane);
    float vx = LP_ALPHA * (di * sx) + (1.0f - LP_ALPHA) * yv.x;
    float vy = LP_ALPHA * (di * sy) + (1.0f - LP_ALPHA) * yv.y;
    float2 o;
    o.x = fminf(fmaxf(vx, 0.f), 1.f);
    o.y = fminf(fmaxf(vy, 0.f), 1.f);
    *(float2*)(nxt + (size_t)i * FDIM + 2 * lane) = o;
}

// ---------------- pooling: segmented (batch sorted), atomic-free ----------------
__global__ void pool_part_k(const float* __restrict__ x, const float* __restrict__ h1,
                            const float* __restrict__ h2, const int* __restrict__ gb,
                            float* __restrict__ part) {
    int g = blockIdx.x, si = blockIdx.y, ch = blockIdx.z;
    int t = threadIdx.x; // 128
    const float* s = (si == 0) ? x : ((si == 1) ? h1 : h2);
    int n0g = gb[g], n1g = gb[g + 1];
    int len = n1g - n0g;
    int per = (len + POOL_CH - 1) / POOL_CH;
    int n0 = n0g + ch * per;
    int n1 = min(n0 + per, n1g);
    float acc = 0.0f;
    for (int n = n0; n < n1; ++n) acc += s[(size_t)n * FDIM + t];
    part[(((g * 3 + si) << 3) + ch) * FDIM + t] = acc;
}

// ---------------- MLP ----------------
__global__ void mlp1_k(const float* __restrict__ part, const int* __restrict__ gb,
                       const float* __restrict__ W1, const float* __restrict__ b1,
                       float* __restrict__ h) {
    int g = blockIdx.x;     // 32
    int t = threadIdx.x;    // 256
    __shared__ float gm[POOLF];
    int cnt = gb[g + 1] - gb[g];
    float inv = 1.0f / fmaxf((float)cnt, 1.0f);
    for (int f = t; f < POOLF; f += 256) {
        int si = f >> 7, fl = f & 127;
        float s = 0.0f;
#pragma unroll
        for (int c = 0; c < POOL_CH; ++c)
            s += part[(((g * 3 + si) << 3) + c) * FDIM + fl];
        gm[f] = s * inv;
    }
    __syncthreads();
    float acc = b1[t];
    for (int k = 0; k < POOLF; ++k) acc = fmaf(gm[k], W1[k * MLP_H + t], acc);
    h[g * MLP_H + t] = fmaxf(acc, 0.0f);
}

__global__ void mlp2_k(const float* __restrict__ h, const float* __restrict__ W2,
                       const float* __restrict__ b2, float* __restrict__ out) {
    int g = blockIdx.x;     // 32
    int t = threadIdx.x;    // 128
    __shared__ float hs[MLP_H];
    for (int k = t; k < MLP_H; k += 128) hs[k] = h[g * MLP_H + k];
    __syncthreads();
    float acc = b2[t];
    for (int k = 0; k < MLP_H; ++k) acc = fmaf(hs[k], W2[k * OUT_F + t], acc);
    out[g * OUT_F + t] = acc;
}

// ---------------- launch ----------------
extern "C" void kernel_launch(void* const* d_in, const int* in_sizes, int n_in,
                              void* d_out, int out_size, void* d_ws, size_t ws_size,
                              hipStream_t stream) {
    const float* x    = (const float*)d_in[0];
    const int*   ei   = (const int*)d_in[1];
    const int*   batch= (const int*)d_in[2];
    const float* W_l1 = (const float*)d_in[3];
    const float* W_r1 = (const float*)d_in[4];
    const float* att1 = (const float*)d_in[5];
    const float* b1   = (const float*)d_in[6];
    const float* W_l2 = (const float*)d_in[7];
    const float* W_r2 = (const float*)d_in[8];
    const float* att2 = (const float*)d_in[9];
    const float* b2   = (const float*)d_in[10];
    const float* mW1  = (const float*)d_in[11];
    const float* mb1  = (const float*)d_in[12];
    const float* mW2  = (const float*)d_in[13];
    const float* mb2  = (const float*)d_in[14];
    float* out = (float*)d_out;

    const int N = in_sizes[2];
    const int E = in_sizes[1] / 2;
    const int* src = ei;
    const int* dst = ei + E;

    char* w = (char*)d_ws;
    auto alloc = [&](size_t bytes) -> char* {
        char* p = w;
        w += (bytes + 255) & ~(size_t)255;
        return p;
    };
    float* bufA = (float*)alloc((size_t)N * FDIM * 4);
    float* bufB = (float*)alloc((size_t)N * FDIM * 4);
    float* bufC = (float*)alloc((size_t)N * FDIM * 4);   // h1 lives here
    float* bufD = (float*)alloc((size_t)N * FDIM * 4);   // h2 lives here
    int* deg     = (int*)alloc((size_t)N * 4);
    int* fill    = (int*)alloc((size_t)N * 4);
    int* row_lp  = (int*)alloc((size_t)(N + 1) * 4);
    int2* elist  = (int2*)alloc((size_t)E * 8);
    float* dinv  = (float*)alloc((size_t)N * 4);
    int* gb      = (int*)alloc((size_t)(NGRAPHS + 1) * 4);
    float* part  = (float*)alloc((size_t)NGRAPHS * 3 * POOL_CH * FDIM * 4);
    float* mlp_h = (float*)alloc((size_t)NGRAPHS * MLP_H * 4);

    const int TB = 256;
    int gE = (E + TB - 1) / TB;
    int gN = (N + TB - 1) / TB;

    // ---- CSR build ----
    hipMemsetAsync(deg, 0, (size_t)N * 4, stream);
    hipMemsetAsync(fill, 0, (size_t)N * 4, stream);
    count_deg_k<<<gE, TB, 0, stream>>>(dst, deg, E);
    gbound_k<<<1, 64, 0, stream>>>(batch, gb, N);
    scan_excl_k<<<1, 1024, 0, stream>>>(deg, row_lp, N);
    dinv_k<<<gN, TB, 0, stream>>>(deg, dinv, N);
    scatter_k<<<gE, TB, 0, stream>>>(src, dst, row_lp, fill, dinv, elist, E);

    int gGemm = (N + 63) / 64;
    int gWave = (N + 3) / 4;   // 4 node-waves per 256-thread block

    // ---- layer 1 ----
    gemm128_k<<<gGemm, 256, 0, stream>>>(x, W_l1, bufA, N);   // xl
    gemm128_k<<<gGemm, 256, 0, stream>>>(x, W_r1, bufB, N);   // xr
    gat_pull_k<<<gWave, 256, 0, stream>>>(bufA, bufB, row_lp, elist, att1, b1, bufC, N);
    lp_pull_k<<<gWave, 256, 0, stream>>>(bufC, bufC, bufA, row_lp, elist, dinv, N);
    lp_pull_k<<<gWave, 256, 0, stream>>>(bufC, bufA, bufC, row_lp, elist, dinv, N);

    // ---- layer 2 ----
    gemm128_k<<<gGemm, 256, 0, stream>>>(bufC, W_l2, bufA, N);
    gemm128_k<<<gGemm, 256, 0, stream>>>(bufC, W_r2, bufB, N);
    gat_pull_k<<<gWave, 256, 0, stream>>>(bufA, bufB, row_lp, elist, att2, b2, bufD, N);
    lp_pull_k<<<gWave, 256, 0, stream>>>(bufD, bufD, bufA, row_lp, elist, dinv, N);
    lp_pull_k<<<gWave, 256, 0, stream>>>(bufD, bufA, bufD, row_lp, elist, dinv, N);

    // ---- pooling (segmented, atomic-free) ----
    pool_part_k<<<dim3(NGRAPHS, 3, POOL_CH), 128, 0, stream>>>(x, bufC, bufD, gb, part);

    // ---- MLP head ----
    mlp1_k<<<NGRAPHS, 256, 0, stream>>>(part, gb, mW1, mb1, mlp_h);
    mlp2_k<<<NGRAPHS, 128, 0, stream>>>(mlp_h, mW2, mb2, out);
}

// Round 5
// 773.461 us; speedup vs baseline: 2.0678x; 1.1161x over previous
//
#include <hip/hip_runtime.h>
#include <math.h>

// ---------------- constants ----------------
#define FDIM 128          // F_IN == HEADS*C_HID == 128
#define NEG_SLOPE 0.2f
#define LP_ALPHA 0.5f
#define NGRAPHS 32
#define POOLF 384         // 3*128
#define MLP_H 256
#define OUT_F 128
#define POOL_CH 8         // chunks per (graph, source) in pooling

#define LRELU(z) ((z) > 0.0f ? (z) : NEG_SLOPE * (z))
#define RFL(v) __builtin_amdgcn_readfirstlane(v)

// ---------------- CSR build ----------------
__global__ void count_deg_k(const int* __restrict__ dst, int* __restrict__ deg, int E) {
    int e = blockIdx.x * blockDim.x + threadIdx.x;
    if (e < E) atomicAdd(&deg[dst[e]], 1);
}

// ---- hierarchical exclusive scan over deg[N] (tiles of 1024) ----
__global__ __launch_bounds__(256) void scan_part_k(const int* __restrict__ deg,
                                                   int* __restrict__ tileSum, int N) {
    int b = blockIdx.x, t = threadIdx.x;
    int base = b * 1024 + t * 4;
    int v = 0;
    if (base + 3 < N) { int4 d = *(const int4*)(deg + base); v = d.x + d.y + d.z + d.w; }
    else if (base < N) {
        v = deg[base];
        if (base + 1 < N) v += deg[base + 1];
        if (base + 2 < N) v += deg[base + 2];
    }
#pragma unroll
    for (int off = 32; off > 0; off >>= 1) v += __shfl_xor(v, off, 64);
    __shared__ int ws[4];
    if ((t & 63) == 0) ws[t >> 6] = v;
    __syncthreads();
    if (t == 0) tileSum[b] = ws[0] + ws[1] + ws[2] + ws[3];
}

// single wave: exclusive scan of tile sums (nt <= 64)
__global__ void scan_tiles_k(const int* __restrict__ tileSum, int* __restrict__ tileOff, int nt) {
    int t = threadIdx.x;   // 64
    int v = (t < nt) ? tileSum[t] : 0;
    int incl = v;
#pragma unroll
    for (int off = 1; off < 64; off <<= 1) {
        int u = __shfl_up(incl, off, 64);
        if (t >= off) incl += u;
    }
    if (t < nt) tileOff[t] = incl - v;
}

// per-tile write-out of row_ptr (+ fused dinv); row_ptr[N] = E (known)
__global__ __launch_bounds__(256) void scan_write_k(const int* __restrict__ deg,
                                                    const int* __restrict__ tileOff,
                                                    int* __restrict__ row_ptr,
                                                    float* __restrict__ dinv, int N, int E) {
    int b = blockIdx.x, t = threadIdx.x;
    int base = b * 1024 + t * 4;
    int d0 = 0, d1 = 0, d2 = 0, d3 = 0;
    if (base + 3 < N) { int4 d = *(const int4*)(deg + base); d0 = d.x; d1 = d.y; d2 = d.z; d3 = d.w; }
    else if (base < N) {
        d0 = deg[base];
        if (base + 1 < N) d1 = deg[base + 1];
        if (base + 2 < N) d2 = deg[base + 2];
    }
    int lsum = d0 + d1 + d2 + d3;
    int lane = t & 63, wv = t >> 6;
    int incl = lsum;
#pragma unroll
    for (int off = 1; off < 64; off <<= 1) {
        int u = __shfl_up(incl, off, 64);
        if (lane >= off) incl += u;
    }
    __shared__ int wsum[4];
    if (lane == 63) wsum[wv] = incl;
    __syncthreads();
    int woff = 0;
#pragma unroll
    for (int k = 0; k < 4; ++k) if (k < wv) woff += wsum[k];
    int off0 = tileOff[b] + woff + (incl - lsum);
    if (base < N)     { row_ptr[base]     = off0;                dinv[base]     = d0 > 0 ? 1.0f / sqrtf((float)d0) : 0.0f; }
    if (base + 1 < N) { row_ptr[base + 1] = off0 + d0;           dinv[base + 1] = d1 > 0 ? 1.0f / sqrtf((float)d1) : 0.0f; }
    if (base + 2 < N) { row_ptr[base + 2] = off0 + d0 + d1;      dinv[base + 2] = d2 > 0 ? 1.0f / sqrtf((float)d2) : 0.0f; }
    if (base + 3 < N) { row_ptr[base + 3] = off0 + d0 + d1 + d2; dinv[base + 3] = d3 > 0 ? 1.0f / sqrtf((float)d3) : 0.0f; }
    if (b == 0 && t == 0) row_ptr[N] = E;
}

// one random 8B nt-store per edge: {src, dinv[src]} packed
__global__ void scatter_k(const int* __restrict__ src, const int* __restrict__ dst,
                          const int* __restrict__ row_ptr, int* __restrict__ fill,
                          const float* __restrict__ dinv, int2* __restrict__ elist, int E) {
    int e = blockIdx.x * blockDim.x + threadIdx.x;
    if (e >= E) return;
    int d = dst[e], s = src[e];
    int pos = atomicAdd(&fill[d], 1);
    unsigned long long v = (unsigned int)s |
                           ((unsigned long long)(unsigned int)__float_as_int(dinv[s]) << 32);
    __builtin_nontemporal_store(v, (unsigned long long*)&elist[row_ptr[d] + pos]);
}

// ---------------- graph boundaries: batch is SORTED -> binary search ----------------
__global__ void gbound_k(const int* __restrict__ batch, int* __restrict__ gb, int N) {
    int g = threadIdx.x;             // 0..NGRAPHS
    if (g > NGRAPHS) return;
    int lo = 0, hi = N;              // first index with batch[i] >= g
    while (lo < hi) {
        int mid = (lo + hi) >> 1;
        if (batch[mid] < g) lo = mid + 1; else hi = mid;
    }
    gb[g] = lo;
}

// ---------------- fused dual node GEMM: Yl = X@Wl, Yr = X@Wr ----------------
// 64 rows/block, 256 threads, 8x4 register tile per output stream; X staged once.
__global__ __launch_bounds__(256) void gemm128x2_k(const float* __restrict__ X,
                                                   const float* __restrict__ Wl,
                                                   const float* __restrict__ Wr,
                                                   float* __restrict__ Yl,
                                                   float* __restrict__ Yr, int N) {
    __shared__ float Xs[FDIM][68];        // [k][r], padded
    int t = threadIdx.x;
    int r0 = blockIdx.x * 64;
    for (int idx = t; idx < 64 * FDIM; idx += 256) {
        int k = idx & 127, r = idx >> 7;
        int row = r0 + r;
        Xs[k][r] = (row < N) ? X[(size_t)row * FDIM + k] : 0.0f;
    }
    __syncthreads();
    int tr = t >> 5;      // 0..7
    int tc = t & 31;      // 0..31
    float accl[8][4] = {{0.f}}, accr[8][4] = {{0.f}};
#pragma unroll 2
    for (int k = 0; k < FDIM; ++k) {
        float4 bl = *(const float4*)(Wl + k * FDIM + tc * 4);   // L1/L2-resident
        float4 br = *(const float4*)(Wr + k * FDIM + tc * 4);
        float4 a0 = *(const float4*)(&Xs[k][tr * 8]);
        float4 a1 = *(const float4*)(&Xs[k][tr * 8 + 4]);
        float av[8] = {a0.x, a0.y, a0.z, a0.w, a1.x, a1.y, a1.z, a1.w};
#pragma unroll
        for (int r = 0; r < 8; ++r) {
            accl[r][0] = fmaf(av[r], bl.x, accl[r][0]);
            accl[r][1] = fmaf(av[r], bl.y, accl[r][1]);
            accl[r][2] = fmaf(av[r], bl.z, accl[r][2]);
            accl[r][3] = fmaf(av[r], bl.w, accl[r][3]);
            accr[r][0] = fmaf(av[r], br.x, accr[r][0]);
            accr[r][1] = fmaf(av[r], br.y, accr[r][1]);
            accr[r][2] = fmaf(av[r], br.z, accr[r][2]);
            accr[r][3] = fmaf(av[r], br.w, accr[r][3]);
        }
    }
#pragma unroll
    for (int r = 0; r < 8; ++r) {
        int row = r0 + tr * 8 + r;
        if (row < N) {
            *(float4*)(Yl + (size_t)row * FDIM + tc * 4) =
                make_float4(accl[r][0], accl[r][1], accl[r][2], accl[r][3]);
            *(float4*)(Yr + (size_t)row * FDIM + tc * 4) =
                make_float4(accr[r][0], accr[r][1], accr[r][2], accr[r][3]);
        }
    }
}

// ---------------- GATv2 pull: online softmax + aggregate + bias + ELU ----------------
// block = 256 = 4 waves; wave handles one node. lane covers channels {2l,2l+1}; head = l>>5.
__global__ __launch_bounds__(256) void gat_pull_k(const float* __restrict__ xl,
                                                  const float* __restrict__ xr,
                                                  const int* __restrict__ row_ptr,
                                                  const int2* __restrict__ elist,
                                                  const float* __restrict__ att,
                                                  const float* __restrict__ bias,
                                                  float* __restrict__ out, int N) {
    int wid = threadIdx.x >> 6;
    int lane = threadIdx.x & 63;
    int i = blockIdx.x * 4 + wid;
    if (i >= N) return;
    float2 at  = *(const float2*)(att + 2 * lane);
    size_t ibase = (size_t)i * FDIM + 2 * lane;
    float2 xrv   = *(const float2*)(xr + ibase);
    float2 xself = *(const float2*)(xl + ibase);

    auto hred = [](float v) {  // sum over the 32 lanes of this head
        v += __shfl_xor(v, 16, 64);
        v += __shfl_xor(v, 8, 64);
        v += __shfl_xor(v, 4, 64);
        v += __shfl_xor(v, 2, 64);
        v += __shfl_xor(v, 1, 64);
        return v;
    };

    // self-loop seeds state0
    float lself = hred(LRELU(xrv.x + xself.x) * at.x + LRELU(xrv.y + xself.y) * at.y);
    float m0 = lself, s0 = 1.0f, a0x = xself.x, a0y = xself.y;
    float m1 = -INFINITY, s1 = 0.0f, a1x = 0.0f, a1y = 0.0f;

    int beg = row_ptr[i], end = row_ptr[i + 1];
    int p = beg;
    for (; p + 3 < end; p += 4) {
        int j0 = RFL(elist[p].x);
        int j1 = RFL(elist[p + 1].x);
        int j2 = RFL(elist[p + 2].x);
        int j3 = RFL(elist[p + 3].x);
        float2 x0 = *(const float2*)(xl + (size_t)j0 * FDIM + 2 * lane);
        float2 x1 = *(const float2*)(xl + (size_t)j1 * FDIM + 2 * lane);
        float2 x2 = *(const float2*)(xl + (size_t)j2 * FDIM + 2 * lane);
        float2 x3 = *(const float2*)(xl + (size_t)j3 * FDIM + 2 * lane);
        float l0 = hred(LRELU(xrv.x + x0.x) * at.x + LRELU(xrv.y + x0.y) * at.y);
        float l1 = hred(LRELU(xrv.x + x1.x) * at.x + LRELU(xrv.y + x1.y) * at.y);
        float l2 = hred(LRELU(xrv.x + x2.x) * at.x + LRELU(xrv.y + x2.y) * at.y);
        float l3 = hred(LRELU(xrv.x + x3.x) * at.x + LRELU(xrv.y + x3.y) * at.y);
        { float mn = fmaxf(m0, l0); float sc = __expf(m0 - mn), pe = __expf(l0 - mn);
          s0 = fmaf(s0, sc, pe); a0x = fmaf(a0x, sc, pe * x0.x); a0y = fmaf(a0y, sc, pe * x0.y); m0 = mn; }
        { float mn = fmaxf(m1, l1); float sc = __expf(m1 - mn), pe = __expf(l1 - mn);
          s1 = fmaf(s1, sc, pe); a1x = fmaf(a1x, sc, pe * x1.x); a1y = fmaf(a1y, sc, pe * x1.y); m1 = mn; }
        { float mn = fmaxf(m0, l2); float sc = __expf(m0 - mn), pe = __expf(l2 - mn);
          s0 = fmaf(s0, sc, pe); a0x = fmaf(a0x, sc, pe * x2.x); a0y = fmaf(a0y, sc, pe * x2.y); m0 = mn; }
        { float mn = fmaxf(m1, l3); float sc = __expf(m1 - mn), pe = __expf(l3 - mn);
          s1 = fmaf(s1, sc, pe); a1x = fmaf(a1x, sc, pe * x3.x); a1y = fmaf(a1y, sc, pe * x3.y); m1 = mn; }
    }
    for (; p < end; ++p) {
        int j0 = RFL(elist[p].x);
        float2 x0 = *(const float2*)(xl + (size_t)j0 * FDIM + 2 * lane);
        float l0 = hred(LRELU(xrv.x + x0.x) * at.x + LRELU(xrv.y + x0.y) * at.y);
        float mn = fmaxf(m0, l0); float sc = __expf(m0 - mn), pe = __expf(l0 - mn);
        s0 = fmaf(s0, sc, pe); a0x = fmaf(a0x, sc, pe * x0.x); a0y = fmaf(a0y, sc, pe * x0.y); m0 = mn;
    }
    // merge the two softmax states; m0 always finite
    float mn = fmaxf(m0, m1);
    float c0 = __expf(m0 - mn);
    float c1 = (m1 == -INFINITY) ? 0.0f : __expf(m1 - mn);
    float s = fmaf(s0, c0, s1 * c1) + 1e-16f;
    float rx = (a0x * c0 + a1x * c1) / s;
    float ry = (a0y * c0 + a1y * c1) / s;
    float2 bv = *(const float2*)(bias + 2 * lane);
    float zx = rx + bv.x, zy = ry + bv.y;
    float2 o;
    o.x = (zx > 0.0f) ? zx : (__expf(zx) - 1.0f);
    o.y = (zy > 0.0f) ? zy : (__expf(zy) - 1.0f);
    *(float2*)(out + ibase) = o;
}

// ---------------- label propagation pull step (unroll-8, packed edge weights) ----------------
__global__ __launch_bounds__(256) void lp_pull_k(const float* __restrict__ y,
                                                 const float* __restrict__ cur,
                                                 float* __restrict__ nxt,
                                                 const int* __restrict__ row_ptr,
                                                 const int2* __restrict__ elist,
                                                 const float* __restrict__ dinv, int N) {
    int wid = threadIdx.x >> 6, lane = threadIdx.x & 63;
    int i = blockIdx.x * 4 + wid;
    if (i >= N) return;
    int beg = row_ptr[i], end = row_ptr[i + 1];
    float ax0 = 0.f, ay0 = 0.f, ax1 = 0.f, ay1 = 0.f;
    float ax2 = 0.f, ay2 = 0.f, ax3 = 0.f, ay3 = 0.f;
    float ax4 = 0.f, ay4 = 0.f, ax5 = 0.f, ay5 = 0.f;
    float ax6 = 0.f, ay6 = 0.f, ax7 = 0.f, ay7 = 0.f;
    int p = beg;
    for (; p + 7 < end; p += 8) {
        int2 e0 = elist[p + 0], e1 = elist[p + 1], e2 = elist[p + 2], e3 = elist[p + 3];
        int2 e4 = elist[p + 4], e5 = elist[p + 5], e6 = elist[p + 6], e7 = elist[p + 7];
        int j0 = RFL(e0.x); float w0 = __int_as_float(RFL(e0.y));
        int j1 = RFL(e1.x); float w1 = __int_as_float(RFL(e1.y));
        int j2 = RFL(e2.x); float w2 = __int_as_float(RFL(e2.y));
        int j3 = RFL(e3.x); float w3 = __int_as_float(RFL(e3.y));
        int j4 = RFL(e4.x); float w4 = __int_as_float(RFL(e4.y));
        int j5 = RFL(e5.x); float w5 = __int_as_float(RFL(e5.y));
        int j6 = RFL(e6.x); float w6 = __int_as_float(RFL(e6.y));
        int j7 = RFL(e7.x); float w7 = __int_as_float(RFL(e7.y));
        float2 v0 = *(const float2*)(cur + (size_t)j0 * FDIM + 2 * lane);
        float2 v1 = *(const float2*)(cur + (size_t)j1 * FDIM + 2 * lane);
        float2 v2 = *(const float2*)(cur + (size_t)j2 * FDIM + 2 * lane);
        float2 v3 = *(const float2*)(cur + (size_t)j3 * FDIM + 2 * lane);
        float2 v4 = *(const float2*)(cur + (size_t)j4 * FDIM + 2 * lane);
        float2 v5 = *(const float2*)(cur + (size_t)j5 * FDIM + 2 * lane);
        float2 v6 = *(const float2*)(cur + (size_t)j6 * FDIM + 2 * lane);
        float2 v7 = *(const float2*)(cur + (size_t)j7 * FDIM + 2 * lane);
        ax0 = fmaf(w0, v0.x, ax0); ay0 = fmaf(w0, v0.y, ay0);
        ax1 = fmaf(w1, v1.x, ax1); ay1 = fmaf(w1, v1.y, ay1);
        ax2 = fmaf(w2, v2.x, ax2); ay2 = fmaf(w2, v2.y, ay2);
        ax3 = fmaf(w3, v3.x, ax3); ay3 = fmaf(w3, v3.y, ay3);
        ax4 = fmaf(w4, v4.x, ax4); ay4 = fmaf(w4, v4.y, ay4);
        ax5 = fmaf(w5, v5.x, ax5); ay5 = fmaf(w5, v5.y, ay5);
        ax6 = fmaf(w6, v6.x, ax6); ay6 = fmaf(w6, v6.y, ay6);
        ax7 = fmaf(w7, v7.x, ax7); ay7 = fmaf(w7, v7.y, ay7);
    }
    for (; p < end; ++p) {
        int2 e0 = elist[p];
        int j0 = RFL(e0.x); float w0 = __int_as_float(RFL(e0.y));
        float2 v0 = *(const float2*)(cur + (size_t)j0 * FDIM + 2 * lane);
        ax0 = fmaf(w0, v0.x, ax0); ay0 = fmaf(w0, v0.y, ay0);
    }
    float sx = ((ax0 + ax1) + (ax2 + ax3)) + ((ax4 + ax5) + (ax6 + ax7));
    float sy = ((ay0 + ay1) + (ay2 + ay3)) + ((ay4 + ay5) + (ay6 + ay7));
    float di = dinv[i];
    float2 yv = *(const float2*)(y + (size_t)i * FDIM + 2 * lane);
    float vx = LP_ALPHA * (di * sx) + (1.0f - LP_ALPHA) * yv.x;
    float vy = LP_ALPHA * (di * sy) + (1.0f - LP_ALPHA) * yv.y;
    float2 o;
    o.x = fminf(fmaxf(vx, 0.f), 1.f);
    o.y = fminf(fmaxf(vy, 0.f), 1.f);
    *(float2*)(nxt + (size_t)i * FDIM + 2 * lane) = o;
}

// ---------------- pooling: segmented (batch sorted), atomic-free ----------------
__global__ void pool_part_k(const float* __restrict__ x, const float* __restrict__ h1,
                            const float* __restrict__ h2, const int* __restrict__ gb,
                            float* __restrict__ part) {
    int g = blockIdx.x, si = blockIdx.y, ch = blockIdx.z;
    int t = threadIdx.x; // 128
    const float* s = (si == 0) ? x : ((si == 1) ? h1 : h2);
    int n0g = gb[g], n1g = gb[g + 1];
    int len = n1g - n0g;
    int per = (len + POOL_CH - 1) / POOL_CH;
    int n0 = n0g + ch * per;
    int n1 = min(n0 + per, n1g);
    float acc = 0.0f;
    for (int n = n0; n < n1; ++n) acc += s[(size_t)n * FDIM + t];
    part[(((g * 3 + si) << 3) + ch) * FDIM + t] = acc;
}

// ---------------- MLP ----------------
__global__ void mlp1_k(const float* __restrict__ part, const int* __restrict__ gb,
                       const float* __restrict__ W1, const float* __restrict__ b1,
                       float* __restrict__ h) {
    int g = blockIdx.x;     // 32
    int t = threadIdx.x;    // 256
    __shared__ float gm[POOLF];
    int cnt = gb[g + 1] - gb[g];
    float inv = 1.0f / fmaxf((float)cnt, 1.0f);
    for (int f = t; f < POOLF; f += 256) {
        int si = f >> 7, fl = f & 127;
        float s = 0.0f;
#pragma unroll
        for (int c = 0; c < POOL_CH; ++c)
            s += part[(((g * 3 + si) << 3) + c) * FDIM + fl];
        gm[f] = s * inv;
    }
    __syncthreads();
    float acc = b1[t];
    for (int k = 0; k < POOLF; ++k) acc = fmaf(gm[k], W1[k * MLP_H + t], acc);
    h[g * MLP_H + t] = fmaxf(acc, 0.0f);
}

__global__ void mlp2_k(const float* __restrict__ h, const float* __restrict__ W2,
                       const float* __restrict__ b2, float* __restrict__ out) {
    int g = blockIdx.x;     // 32
    int t = threadIdx.x;    // 128
    __shared__ float hs[MLP_H];
    for (int k = t; k < MLP_H; k += 128) hs[k] = h[g * MLP_H + k];
    __syncthreads();
    float acc = b2[t];
    for (int k = 0; k < MLP_H; ++k) acc = fmaf(hs[k], W2[k * OUT_F + t], acc);
    out[g * OUT_F + t] = acc;
}

// ---------------- launch ----------------
extern "C" void kernel_launch(void* const* d_in, const int* in_sizes, int n_in,
                              void* d_out, int out_size, void* d_ws, size_t ws_size,
                              hipStream_t stream) {
    const float* x    = (const float*)d_in[0];
    const int*   ei   = (const int*)d_in[1];
    const int*   batch= (const int*)d_in[2];
    const float* W_l1 = (const float*)d_in[3];
    const float* W_r1 = (const float*)d_in[4];
    const float* att1 = (const float*)d_in[5];
    const float* b1   = (const float*)d_in[6];
    const float* W_l2 = (const float*)d_in[7];
    const float* W_r2 = (const float*)d_in[8];
    const float* att2 = (const float*)d_in[9];
    const float* b2   = (const float*)d_in[10];
    const float* mW1  = (const float*)d_in[11];
    const float* mb1  = (const float*)d_in[12];
    const float* mW2  = (const float*)d_in[13];
    const float* mb2  = (const float*)d_in[14];
    float* out = (float*)d_out;

    const int N = in_sizes[2];
    const int E = in_sizes[1] / 2;
    const int* src = ei;
    const int* dst = ei + E;

    char* w = (char*)d_ws;
    auto alloc = [&](size_t bytes) -> char* {
        char* p = w;
        w += (bytes + 255) & ~(size_t)255;
        return p;
    };
    float* bufA = (float*)alloc((size_t)N * FDIM * 4);
    float* bufB = (float*)alloc((size_t)N * FDIM * 4);
    float* bufC = (float*)alloc((size_t)N * FDIM * 4);   // h1 lives here
    float* bufD = (float*)alloc((size_t)N * FDIM * 4);   // h2 lives here
    int* deg     = (int*)alloc((size_t)N * 4);
    int* fill    = (int*)alloc((size_t)N * 4);
    int* row_lp  = (int*)alloc((size_t)(N + 1) * 4);
    int2* elist  = (int2*)alloc((size_t)E * 8);
    float* dinv  = (float*)alloc((size_t)N * 4);
    int* gb      = (int*)alloc((size_t)(NGRAPHS + 1) * 4);
    int* tileSum = (int*)alloc((size_t)64 * 4);
    int* tileOff = (int*)alloc((size_t)64 * 4);
    float* part  = (float*)alloc((size_t)NGRAPHS * 3 * POOL_CH * FDIM * 4);
    float* mlp_h = (float*)alloc((size_t)NGRAPHS * MLP_H * 4);

    const int TB = 256;
    int gE = (E + TB - 1) / TB;
    int nTiles = (N + 1023) / 1024;   // 49 for N=50000

    // ---- CSR build ----
    hipMemsetAsync(deg, 0, (size_t)N * 4, stream);
    hipMemsetAsync(fill, 0, (size_t)N * 4, stream);
    count_deg_k<<<gE, TB, 0, stream>>>(dst, deg, E);
    gbound_k<<<1, 64, 0, stream>>>(batch, gb, N);
    scan_part_k<<<nTiles, 256, 0, stream>>>(deg, tileSum, N);
    scan_tiles_k<<<1, 64, 0, stream>>>(tileSum, tileOff, nTiles);
    scan_write_k<<<nTiles, 256, 0, stream>>>(deg, tileOff, row_lp, dinv, N, E);
    scatter_k<<<gE, TB, 0, stream>>>(src, dst, row_lp, fill, dinv, elist, E);

    int gGemm = (N + 63) / 64;
    int gWave = (N + 3) / 4;   // 4 node-waves per 256-thread block

    // ---- layer 1 ----
    gemm128x2_k<<<gGemm, 256, 0, stream>>>(x, W_l1, W_r1, bufA, bufB, N);
    gat_pull_k<<<gWave, 256, 0, stream>>>(bufA, bufB, row_lp, elist, att1, b1, bufC, N);
    lp_pull_k<<<gWave, 256, 0, stream>>>(bufC, bufC, bufA, row_lp, elist, dinv, N);
    lp_pull_k<<<gWave, 256, 0, stream>>>(bufC, bufA, bufC, row_lp, elist, dinv, N);

    // ---- layer 2 ----
    gemm128x2_k<<<gGemm, 256, 0, stream>>>(bufC, W_l2, W_r2, bufA, bufB, N);
    gat_pull_k<<<gWave, 256, 0, stream>>>(bufA, bufB, row_lp, elist, att2, b2, bufD, N);
    lp_pull_k<<<gWave, 256, 0, stream>>>(bufD, bufD, bufA, row_lp, elist, dinv, N);
    lp_pull_k<<<gWave, 256, 0, stream>>>(bufD, bufA, bufD, row_lp, elist, dinv, N);

    // ---- pooling (segmented, atomic-free) ----
    pool_part_k<<<dim3(NGRAPHS, 3, POOL_CH), 128, 0, stream>>>(x, bufC, bufD, gb, part);

    // ---- MLP head ----
    mlp1_k<<<NGRAPHS, 256, 0, stream>>>(part, gb, mW1, mb1, mlp_h);
    mlp2_k<<<NGRAPHS, 128, 0, stream>>>(mlp_h, mW2, mb2, out);
}

// Round 6
// 739.015 us; speedup vs baseline: 2.1642x; 1.0466x over previous
//
#include <hip/hip_runtime.h>
#include <math.h>

// ---------------- constants ----------------
#define FDIM 128          // F_IN == HEADS*C_HID == 128
#define NEG_SLOPE 0.2f
#define LP_ALPHA 0.5f
#define NGRAPHS 32
#define POOLF 384         // 3*128
#define MLP_H 256
#define OUT_F 128
#define POOL_CH 8         // chunks per (graph, source) in pooling

#define LRELU(z) ((z) > 0.0f ? (z) : NEG_SLOPE * (z))

// ---------------- CSR build ----------------
__global__ void count_deg_k(const int* __restrict__ dst, int* __restrict__ deg, int E) {
    int e = blockIdx.x * blockDim.x + threadIdx.x;
    if (e < E) atomicAdd(&deg[dst[e]], 1);
}

// ---- hierarchical exclusive scan over deg[N] (tiles of 1024) ----
__global__ __launch_bounds__(256) void scan_part_k(const int* __restrict__ deg,
                                                   int* __restrict__ tileSum, int N) {
    int b = blockIdx.x, t = threadIdx.x;
    int base = b * 1024 + t * 4;
    int v = 0;
    if (base + 3 < N) { int4 d = *(const int4*)(deg + base); v = d.x + d.y + d.z + d.w; }
    else if (base < N) {
        v = deg[base];
        if (base + 1 < N) v += deg[base + 1];
        if (base + 2 < N) v += deg[base + 2];
    }
#pragma unroll
    for (int off = 32; off > 0; off >>= 1) v += __shfl_xor(v, off, 64);
    __shared__ int ws[4];
    if ((t & 63) == 0) ws[t >> 6] = v;
    __syncthreads();
    if (t == 0) tileSum[b] = ws[0] + ws[1] + ws[2] + ws[3];
}

// single wave: exclusive scan of tile sums (nt <= 64)
__global__ void scan_tiles_k(const int* __restrict__ tileSum, int* __restrict__ tileOff, int nt) {
    int t = threadIdx.x;   // 64
    int v = (t < nt) ? tileSum[t] : 0;
    int incl = v;
#pragma unroll
    for (int off = 1; off < 64; off <<= 1) {
        int u = __shfl_up(incl, off, 64);
        if (t >= off) incl += u;
    }
    if (t < nt) tileOff[t] = incl - v;
}

// per-tile write-out of row_ptr + cursor copy (+ fused dinv); row_ptr[N] = E (known)
__global__ __launch_bounds__(256) void scan_write_k(const int* __restrict__ deg,
                                                    const int* __restrict__ tileOff,
                                                    int* __restrict__ row_ptr,
                                                    int* __restrict__ cursor,
                                                    float* __restrict__ dinv, int N, int E) {
    int b = blockIdx.x, t = threadIdx.x;
    int base = b * 1024 + t * 4;
    int d0 = 0, d1 = 0, d2 = 0, d3 = 0;
    if (base + 3 < N) { int4 d = *(const int4*)(deg + base); d0 = d.x; d1 = d.y; d2 = d.z; d3 = d.w; }
    else if (base < N) {
        d0 = deg[base];
        if (base + 1 < N) d1 = deg[base + 1];
        if (base + 2 < N) d2 = deg[base + 2];
    }
    int lsum = d0 + d1 + d2 + d3;
    int lane = t & 63, wv = t >> 6;
    int incl = lsum;
#pragma unroll
    for (int off = 1; off < 64; off <<= 1) {
        int u = __shfl_up(incl, off, 64);
        if (lane >= off) incl += u;
    }
    __shared__ int wsum[4];
    if (lane == 63) wsum[wv] = incl;
    __syncthreads();
    int woff = 0;
#pragma unroll
    for (int k = 0; k < 4; ++k) if (k < wv) woff += wsum[k];
    int off0 = tileOff[b] + woff + (incl - lsum);
    if (base < N)     { row_ptr[base]     = off0;                cursor[base]     = off0;
                        dinv[base]     = d0 > 0 ? 1.0f / sqrtf((float)d0) : 0.0f; }
    if (base + 1 < N) { row_ptr[base + 1] = off0 + d0;           cursor[base + 1] = off0 + d0;
                        dinv[base + 1] = d1 > 0 ? 1.0f / sqrtf((float)d1) : 0.0f; }
    if (base + 2 < N) { row_ptr[base + 2] = off0 + d0 + d1;      cursor[base + 2] = off0 + d0 + d1;
                        dinv[base + 2] = d2 > 0 ? 1.0f / sqrtf((float)d2) : 0.0f; }
    if (base + 3 < N) { row_ptr[base + 3] = off0 + d0 + d1 + d2; cursor[base + 3] = off0 + d0 + d1 + d2;
                        dinv[base + 3] = d3 > 0 ? 1.0f / sqrtf((float)d3) : 0.0f; }
    if (b == 0 && t == 0) row_ptr[N] = E;
}

// one random 8B nt-store per edge: {src, dinv[src]}; cursor gives absolute slot
__global__ void scatter_k(const int* __restrict__ src, const int* __restrict__ dst,
                          int* __restrict__ cursor, const float* __restrict__ dinv,
                          int2* __restrict__ elist, int E) {
    int e = blockIdx.x * blockDim.x + threadIdx.x;
    if (e >= E) return;
    int d = dst[e], s = src[e];
    int pos = atomicAdd(&cursor[d], 1);
    unsigned long long v = (unsigned int)s |
                           ((unsigned long long)(unsigned int)__float_as_int(dinv[s]) << 32);
    __builtin_nontemporal_store(v, (unsigned long long*)&elist[pos]);
}

// ---------------- graph boundaries: batch is SORTED -> binary search ----------------
__global__ void gbound_k(const int* __restrict__ batch, int* __restrict__ gb, int N) {
    int g = threadIdx.x;             // 0..NGRAPHS
    if (g > NGRAPHS) return;
    int lo = 0, hi = N;              // first index with batch[i] >= g
    while (lo < hi) {
        int mid = (lo + hi) >> 1;
        if (batch[mid] < g) lo = mid + 1; else hi = mid;
    }
    gb[g] = lo;
}

// ---------------- fused dual node GEMM: Yl = X@Wl, Yr = X@Wr ----------------
__global__ __launch_bounds__(256) void gemm128x2_k(const float* __restrict__ X,
                                                   const float* __restrict__ Wl,
                                                   const float* __restrict__ Wr,
                                                   float* __restrict__ Yl,
                                                   float* __restrict__ Yr, int N) {
    __shared__ float Xs[FDIM][68];        // [k][r], padded
    int t = threadIdx.x;
    int r0 = blockIdx.x * 64;
    for (int idx = t; idx < 64 * FDIM; idx += 256) {
        int k = idx & 127, r = idx >> 7;
        int row = r0 + r;
        Xs[k][r] = (row < N) ? X[(size_t)row * FDIM + k] : 0.0f;
    }
    __syncthreads();
    int tr = t >> 5;      // 0..7
    int tc = t & 31;      // 0..31
    float accl[8][4] = {{0.f}}, accr[8][4] = {{0.f}};
#pragma unroll 2
    for (int k = 0; k < FDIM; ++k) {
        float4 bl = *(const float4*)(Wl + k * FDIM + tc * 4);   // L1/L2-resident
        float4 br = *(const float4*)(Wr + k * FDIM + tc * 4);
        float4 a0 = *(const float4*)(&Xs[k][tr * 8]);
        float4 a1 = *(const float4*)(&Xs[k][tr * 8 + 4]);
        float av[8] = {a0.x, a0.y, a0.z, a0.w, a1.x, a1.y, a1.z, a1.w};
#pragma unroll
        for (int r = 0; r < 8; ++r) {
            accl[r][0] = fmaf(av[r], bl.x, accl[r][0]);
            accl[r][1] = fmaf(av[r], bl.y, accl[r][1]);
            accl[r][2] = fmaf(av[r], bl.z, accl[r][2]);
            accl[r][3] = fmaf(av[r], bl.w, accl[r][3]);
            accr[r][0] = fmaf(av[r], br.x, accr[r][0]);
            accr[r][1] = fmaf(av[r], br.y, accr[r][1]);
            accr[r][2] = fmaf(av[r], br.z, accr[r][2]);
            accr[r][3] = fmaf(av[r], br.w, accr[r][3]);
        }
    }
#pragma unroll
    for (int r = 0; r < 8; ++r) {
        int row = r0 + tr * 8 + r;
        if (row < N) {
            *(float4*)(Yl + (size_t)row * FDIM + tc * 4) =
                make_float4(accl[r][0], accl[r][1], accl[r][2], accl[r][3]);
            *(float4*)(Yr + (size_t)row * FDIM + tc * 4) =
                make_float4(accr[r][0], accr[r][1], accr[r][2], accr[r][3]);
        }
    }
}

// ---------------- GATv2 pull: half-wave edge pairing ----------------
// wave = 1 node. lane l: half = l>>5 (even/odd edges), lh = l&31 holds channels
// [4lh,4lh+4) (lh<16 -> head0, lh>=16 -> head1). Head-logit reduce = 4 shfls
// within 16-lane groups, covering TWO edges per wave step. Two softmax states
// per lane (step parity) for ILP; merged in-lane then across halves (shfl 32).
__global__ __launch_bounds__(256) void gat_pull_k(const float* __restrict__ xl,
                                                  const float* __restrict__ xr,
                                                  const int* __restrict__ row_ptr,
                                                  const int2* __restrict__ elist,
                                                  const float* __restrict__ att,
                                                  const float* __restrict__ bias,
                                                  float* __restrict__ out, int N) {
    int wid = threadIdx.x >> 6;
    int lane = threadIdx.x & 63;
    int half = lane >> 5;
    int lh = lane & 31;
    int i = blockIdx.x * 4 + wid;
    if (i >= N) return;
    float4 at = *(const float4*)(att + 4 * lh);
    size_t ibase = (size_t)i * FDIM + 4 * lh;
    float4 xrv = *(const float4*)(xr + ibase);
    float4 xs  = *(const float4*)(xl + ibase);

    auto qdot = [&](float4 xv) {   // head logit: reduce over this 16-lane group
        float v = LRELU(xrv.x + xv.x) * at.x + LRELU(xrv.y + xv.y) * at.y
                + LRELU(xrv.z + xv.z) * at.z + LRELU(xrv.w + xv.w) * at.w;
        v += __shfl_xor(v, 8, 64);
        v += __shfl_xor(v, 4, 64);
        v += __shfl_xor(v, 2, 64);
        v += __shfl_xor(v, 1, 64);
        return v;
    };

    // self-loop seeds half-A state0; half B starts empty
    float lself = qdot(xs);
    float m0 = half ? -INFINITY : lself;
    float s0 = half ? 0.0f : 1.0f;
    float4 a0 = half ? make_float4(0.f, 0.f, 0.f, 0.f) : xs;
    float m1 = -INFINITY, s1 = 0.0f;
    float4 a1 = make_float4(0.f, 0.f, 0.f, 0.f);

    int beg = row_ptr[i], end = row_ptr[i + 1];
    for (int p = beg; p < end; p += 4) {
        int i0 = p + half, i1 = p + 2 + half;
        bool v0 = i0 < end, v1 = i1 < end;
        int j0 = elist[min(i0, end - 1)].x;
        int j1 = elist[min(i1, end - 1)].x;
        float4 x0 = *(const float4*)(xl + (size_t)j0 * FDIM + 4 * lh);
        float4 x1 = *(const float4*)(xl + (size_t)j1 * FDIM + 4 * lh);
        float l0 = qdot(x0);
        float l1 = qdot(x1);
        if (v0) {   // uniform within each half-wave
            float mn = fmaxf(m0, l0);
            float sc = __expf(m0 - mn), pe = __expf(l0 - mn);   // m0=-inf ok: exp(-inf)=0
            s0 = fmaf(s0, sc, pe);
            a0.x = fmaf(a0.x, sc, pe * x0.x); a0.y = fmaf(a0.y, sc, pe * x0.y);
            a0.z = fmaf(a0.z, sc, pe * x0.z); a0.w = fmaf(a0.w, sc, pe * x0.w);
            m0 = mn;
        }
        if (v1) {
            float mn = fmaxf(m1, l1);
            float sc = __expf(m1 - mn), pe = __expf(l1 - mn);
            s1 = fmaf(s1, sc, pe);
            a1.x = fmaf(a1.x, sc, pe * x1.x); a1.y = fmaf(a1.y, sc, pe * x1.y);
            a1.z = fmaf(a1.z, sc, pe * x1.z); a1.w = fmaf(a1.w, sc, pe * x1.w);
            m1 = mn;
        }
    }
    // in-lane merge (state1 into state0); guards handle -inf states
    {
        float mn = fmaxf(m0, m1);
        float c0 = (m0 == -INFINITY) ? 0.0f : __expf(m0 - mn);
        float c1 = (m1 == -INFINITY) ? 0.0f : __expf(m1 - mn);
        s0 = s0 * c0 + s1 * c1;
        a0.x = a0.x * c0 + a1.x * c1; a0.y = a0.y * c0 + a1.y * c1;
        a0.z = a0.z * c0 + a1.z * c1; a0.w = a0.w * c0 + a1.w * c1;
        m0 = mn;
    }
    // cross-half merge via shfl_xor(32); both halves compute same result
    {
        float pm = __shfl_xor(m0, 32, 64);
        float ps = __shfl_xor(s0, 32, 64);
        float px = __shfl_xor(a0.x, 32, 64), py = __shfl_xor(a0.y, 32, 64);
        float pz = __shfl_xor(a0.z, 32, 64), pw = __shfl_xor(a0.w, 32, 64);
        float mn = fmaxf(m0, pm);
        float c0 = (m0 == -INFINITY) ? 0.0f : __expf(m0 - mn);
        float c1 = (pm == -INFINITY) ? 0.0f : __expf(pm - mn);
        s0 = s0 * c0 + ps * c1;
        a0.x = a0.x * c0 + px * c1; a0.y = a0.y * c0 + py * c1;
        a0.z = a0.z * c0 + pz * c1; a0.w = a0.w * c0 + pw * c1;
    }
    if (half == 0) {
        float inv = 1.0f / (s0 + 1e-16f);
        float4 bv = *(const float4*)(bias + 4 * lh);
        float zx = a0.x * inv + bv.x, zy = a0.y * inv + bv.y;
        float zz = a0.z * inv + bv.z, zw = a0.w * inv + bv.w;
        float4 o;
        o.x = (zx > 0.0f) ? zx : (__expf(zx) - 1.0f);
        o.y = (zy > 0.0f) ? zy : (__expf(zy) - 1.0f);
        o.z = (zz > 0.0f) ? zz : (__expf(zz) - 1.0f);
        o.w = (zw > 0.0f) ? zw : (__expf(zw) - 1.0f);
        *(float4*)(out + ibase) = o;
    }
}

// ---------------- label propagation pull: half-wave edge pairing ----------------
// wave = 1 node; half-wave A takes even edges, B odd; lane holds 4 channels.
// 8 edges per loop step (4 guarded indices per half), linear merge via shfl(32).
__global__ __launch_bounds__(256) void lp_pull_k(const float* __restrict__ y,
                                                 const float* __restrict__ cur,
                                                 float* __restrict__ nxt,
                                                 const int* __restrict__ row_ptr,
                                                 const int2* __restrict__ elist,
                                                 const float* __restrict__ dinv, int N) {
    int wid = threadIdx.x >> 6, lane = threadIdx.x & 63;
    int half = lane >> 5, lh = lane & 31;
    int i = blockIdx.x * 4 + wid;
    if (i >= N) return;
    int beg = row_ptr[i], end = row_ptr[i + 1];
    float4 a0 = make_float4(0.f, 0.f, 0.f, 0.f), a1 = a0, a2 = a0, a3 = a0;
    for (int p = beg; p < end; p += 8) {
        int i0 = p + half, i1 = p + 2 + half, i2 = p + 4 + half, i3 = p + 6 + half;
        int2 e0 = elist[min(i0, end - 1)];
        int2 e1 = elist[min(i1, end - 1)];
        int2 e2 = elist[min(i2, end - 1)];
        int2 e3 = elist[min(i3, end - 1)];
        float w0 = (i0 < end) ? __int_as_float(e0.y) : 0.0f;
        float w1 = (i1 < end) ? __int_as_float(e1.y) : 0.0f;
        float w2 = (i2 < end) ? __int_as_float(e2.y) : 0.0f;
        float w3 = (i3 < end) ? __int_as_float(e3.y) : 0.0f;
        float4 x0 = *(const float4*)(cur + (size_t)e0.x * FDIM + 4 * lh);
        float4 x1 = *(const float4*)(cur + (size_t)e1.x * FDIM + 4 * lh);
        float4 x2 = *(const float4*)(cur + (size_t)e2.x * FDIM + 4 * lh);
        float4 x3 = *(const float4*)(cur + (size_t)e3.x * FDIM + 4 * lh);
        a0.x = fmaf(w0, x0.x, a0.x); a0.y = fmaf(w0, x0.y, a0.y);
        a0.z = fmaf(w0, x0.z, a0.z); a0.w = fmaf(w0, x0.w, a0.w);
        a1.x = fmaf(w1, x1.x, a1.x); a1.y = fmaf(w1, x1.y, a1.y);
        a1.z = fmaf(w1, x1.z, a1.z); a1.w = fmaf(w1, x1.w, a1.w);
        a2.x = fmaf(w2, x2.x, a2.x); a2.y = fmaf(w2, x2.y, a2.y);
        a2.z = fmaf(w2, x2.z, a2.z); a2.w = fmaf(w2, x2.w, a2.w);
        a3.x = fmaf(w3, x3.x, a3.x); a3.y = fmaf(w3, x3.y, a3.y);
        a3.z = fmaf(w3, x3.z, a3.z); a3.w = fmaf(w3, x3.w, a3.w);
    }
    float4 a;
    a.x = (a0.x + a1.x) + (a2.x + a3.x);
    a.y = (a0.y + a1.y) + (a2.y + a3.y);
    a.z = (a0.z + a1.z) + (a2.z + a3.z);
    a.w = (a0.w + a1.w) + (a2.w + a3.w);
    a.x += __shfl_xor(a.x, 32, 64);
    a.y += __shfl_xor(a.y, 32, 64);
    a.z += __shfl_xor(a.z, 32, 64);
    a.w += __shfl_xor(a.w, 32, 64);
    if (half == 0) {
        float di = dinv[i];
        size_t ibase = (size_t)i * FDIM + 4 * lh;
        float4 yv = *(const float4*)(y + ibase);
        float4 o;
        o.x = fminf(fmaxf(fmaf(LP_ALPHA * di, a.x, (1.0f - LP_ALPHA) * yv.x), 0.f), 1.f);
        o.y = fminf(fmaxf(fmaf(LP_ALPHA * di, a.y, (1.0f - LP_ALPHA) * yv.y), 0.f), 1.f);
        o.z = fminf(fmaxf(fmaf(LP_ALPHA * di, a.z, (1.0f - LP_ALPHA) * yv.z), 0.f), 1.f);
        o.w = fminf(fmaxf(fmaf(LP_ALPHA * di, a.w, (1.0f - LP_ALPHA) * yv.w), 0.f), 1.f);
        *(float4*)(nxt + ibase) = o;
    }
}

// ---------------- pooling: segmented (batch sorted), atomic-free ----------------
__global__ void pool_part_k(const float* __restrict__ x, const float* __restrict__ h1,
                            const float* __restrict__ h2, const int* __restrict__ gb,
                            float* __restrict__ part) {
    int g = blockIdx.x, si = blockIdx.y, ch = blockIdx.z;
    int t = threadIdx.x; // 128
    const float* s = (si == 0) ? x : ((si == 1) ? h1 : h2);
    int n0g = gb[g], n1g = gb[g + 1];
    int len = n1g - n0g;
    int per = (len + POOL_CH - 1) / POOL_CH;
    int n0 = n0g + ch * per;
    int n1 = min(n0 + per, n1g);
    float acc = 0.0f;
    for (int n = n0; n < n1; ++n) acc += s[(size_t)n * FDIM + t];
    part[(((g * 3 + si) << 3) + ch) * FDIM + t] = acc;
}

// ---------------- MLP ----------------
__global__ void mlp1_k(const float* __restrict__ part, const int* __restrict__ gb,
                       const float* __restrict__ W1, const float* __restrict__ b1,
                       float* __restrict__ h) {
    int g = blockIdx.x;     // 32
    int t = threadIdx.x;    // 256
    __shared__ float gm[POOLF];
    int cnt = gb[g + 1] - gb[g];
    float inv = 1.0f / fmaxf((float)cnt, 1.0f);
    for (int f = t; f < POOLF; f += 256) {
        int si = f >> 7, fl = f & 127;
        float s = 0.0f;
#pragma unroll
        for (int c = 0; c < POOL_CH; ++c)
            s += part[(((g * 3 + si) << 3) + c) * FDIM + fl];
        gm[f] = s * inv;
    }
    __syncthreads();
    float acc = b1[t];
    for (int k = 0; k < POOLF; ++k) acc = fmaf(gm[k], W1[k * MLP_H + t], acc);
    h[g * MLP_H + t] = fmaxf(acc, 0.0f);
}

__global__ void mlp2_k(const float* __restrict__ h, const float* __restrict__ W2,
                       const float* __restrict__ b2, float* __restrict__ out) {
    int g = blockIdx.x;     // 32
    int t = threadIdx.x;    // 128
    __shared__ float hs[MLP_H];
    for (int k = t; k < MLP_H; k += 128) hs[k] = h[g * MLP_H + k];
    __syncthreads();
    float acc = b2[t];
    for (int k = 0; k < MLP_H; ++k) acc = fmaf(hs[k], W2[k * OUT_F + t], acc);
    out[g * OUT_F + t] = acc;
}

// ---------------- launch ----------------
extern "C" void kernel_launch(void* const* d_in, const int* in_sizes, int n_in,
                              void* d_out, int out_size, void* d_ws, size_t ws_size,
                              hipStream_t stream) {
    const float* x    = (const float*)d_in[0];
    const int*   ei   = (const int*)d_in[1];
    const int*   batch= (const int*)d_in[2];
    const float* W_l1 = (const float*)d_in[3];
    const float* W_r1 = (const float*)d_in[4];
    const float* att1 = (const float*)d_in[5];
    const float* b1   = (const float*)d_in[6];
    const float* W_l2 = (const float*)d_in[7];
    const float* W_r2 = (const float*)d_in[8];
    const float* att2 = (const float*)d_in[9];
    const float* b2   = (const float*)d_in[10];
    const float* mW1  = (const float*)d_in[11];
    const float* mb1  = (const float*)d_in[12];
    const float* mW2  = (const float*)d_in[13];
    const float* mb2  = (const float*)d_in[14];
    float* out = (float*)d_out;

    const int N = in_sizes[2];
    const int E = in_sizes[1] / 2;
    const int* src = ei;
    const int* dst = ei + E;

    char* w = (char*)d_ws;
    auto alloc = [&](size_t bytes) -> char* {
        char* p = w;
        w += (bytes + 255) & ~(size_t)255;
        return p;
    };
    float* bufA = (float*)alloc((size_t)N * FDIM * 4);
    float* bufB = (float*)alloc((size_t)N * FDIM * 4);
    float* bufC = (float*)alloc((size_t)N * FDIM * 4);   // h1 lives here
    float* bufD = (float*)alloc((size_t)N * FDIM * 4);   // h2 lives here
    int* deg     = (int*)alloc((size_t)N * 4);
    int* cursor  = (int*)alloc((size_t)N * 4);
    int* row_lp  = (int*)alloc((size_t)(N + 1) * 4);
    int2* elist  = (int2*)alloc((size_t)E * 8);
    float* dinv  = (float*)alloc((size_t)N * 4);
    int* gb      = (int*)alloc((size_t)(NGRAPHS + 1) * 4);
    int* tileSum = (int*)alloc((size_t)64 * 4);
    int* tileOff = (int*)alloc((size_t)64 * 4);
    float* part  = (float*)alloc((size_t)NGRAPHS * 3 * POOL_CH * FDIM * 4);
    float* mlp_h = (float*)alloc((size_t)NGRAPHS * MLP_H * 4);

    const int TB = 256;
    int gE = (E + TB - 1) / TB;
    int nTiles = (N + 1023) / 1024;   // 49 for N=50000

    // ---- CSR build ----
    hipMemsetAsync(deg, 0, (size_t)N * 4, stream);
    count_deg_k<<<gE, TB, 0, stream>>>(dst, deg, E);
    gbound_k<<<1, 64, 0, stream>>>(batch, gb, N);
    scan_part_k<<<nTiles, 256, 0, stream>>>(deg, tileSum, N);
    scan_tiles_k<<<1, 64, 0, stream>>>(tileSum, tileOff, nTiles);
    scan_write_k<<<nTiles, 256, 0, stream>>>(deg, tileOff, row_lp, cursor, dinv, N, E);
    scatter_k<<<gE, TB, 0, stream>>>(src, dst, cursor, dinv, elist, E);

    int gGemm = (N + 63) / 64;
    int gWave = (N + 3) / 4;   // 4 node-waves per 256-thread block

    // ---- layer 1 ----
    gemm128x2_k<<<gGemm, 256, 0, stream>>>(x, W_l1, W_r1, bufA, bufB, N);
    gat_pull_k<<<gWave, 256, 0, stream>>>(bufA, bufB, row_lp, elist, att1, b1, bufC, N);
    lp_pull_k<<<gWave, 256, 0, stream>>>(bufC, bufC, bufA, row_lp, elist, dinv, N);
    lp_pull_k<<<gWave, 256, 0, stream>>>(bufC, bufA, bufC, row_lp, elist, dinv, N);

    // ---- layer 2 ----
    gemm128x2_k<<<gGemm, 256, 0, stream>>>(bufC, W_l2, W_r2, bufA, bufB, N);
    gat_pull_k<<<gWave, 256, 0, stream>>>(bufA, bufB, row_lp, elist, att2, b2, bufD, N);
    lp_pull_k<<<gWave, 256, 0, stream>>>(bufD, bufD, bufA, row_lp, elist, dinv, N);
    lp_pull_k<<<gWave, 256, 0, stream>>>(bufD, bufA, bufD, row_lp, elist, dinv, N);

    // ---- pooling (segmented, atomic-free) ----
    pool_part_k<<<dim3(NGRAPHS, 3, POOL_CH), 128, 0, stream>>>(x, bufC, bufD, gb, part);

    // ---- MLP head ----
    mlp1_k<<<NGRAPHS, 256, 0, stream>>>(part, gb, mW1, mb1, mlp_h);
    mlp2_k<<<NGRAPHS, 128, 0, stream>>>(mlp_h, mW2, mb2, out);
}